// Round 2
// baseline (658.233 us; speedup 1.0000x reference)
//
#include <hip/hip_runtime.h>
#include <stdint.h>
#include <math.h>

typedef unsigned short u16;
typedef __attribute__((ext_vector_type(8))) short bf16x8;
typedef __attribute__((ext_vector_type(8))) short short8;
typedef __attribute__((ext_vector_type(4))) float f32x4;
typedef __attribute__((ext_vector_type(4))) unsigned short u16x4;

#define NB 16
#define TDr 256
#define TPr 1024
#define DM 512
#define NH 8
#define DHEAD 64

__device__ __forceinline__ float us2f(u16 u) {
  union { float f; unsigned int i; } x; x.i = ((unsigned int)u) << 16; return x.f;
}
__device__ __forceinline__ u16 f2us(float f) {
  union { float fl; unsigned int i; } x; x.fl = f;
  unsigned int u = x.i;
  return (u16)((u + 0x7fffu + ((u >> 16) & 1u)) >> 16);  // RNE
}

// ---------------------------------------------------------------------------
// dtype detect: if raw u16 stream (bf16 view) contains huge magnitudes, the
// underlying data is f32 (random mantissa halves decode to giant exponents).
// ---------------------------------------------------------------------------
__global__ __launch_bounds__(64) void detect_kernel(const u16* __restrict__ raw,
                                                    int* __restrict__ flag)
{
  const int lane = threadIdx.x;
  float mx = 0.f;
  for (int i = lane; i < 256; i += 64) {
    float v = us2f(raw[i]);
    v = fabsf(v);
    if (isfinite(v)) mx = fmaxf(mx, v); else mx = 1e30f;
  }
#pragma unroll
  for (int o = 32; o; o >>= 1) mx = fmaxf(mx, __shfl_xor(mx, o));
  if (lane == 0) flag[0] = (mx > 1e10f) ? 1 : 0;
}

// ---------------------------------------------------------------------------
// canonicalize all float tensors to bf16 arena (copy or f32->bf16 per flag)
// ---------------------------------------------------------------------------
struct CvtDesc { const void* src; unsigned long dst_off; int n; };
struct CvtTable { CvtDesc d[42]; };

__global__ __launch_bounds__(256) void cvt_kernel(CvtTable t, u16* __restrict__ base,
                                                  const int* __restrict__ flag)
{
  const CvtDesc d = t.d[blockIdx.y];
  u16* dst = base + d.dst_off;
  const int isf32 = flag[0];
  const int stride = gridDim.x * 256;
  const int tid0 = blockIdx.x * 256 + threadIdx.x;
  if (d.n >= 8) {  // all big tensors are multiples of 8
    const int n8 = d.n >> 3;
    if (isf32) {
      const float* s = (const float*)d.src;
      for (int i = tid0; i < n8; i += stride) {
        f32x4 a = *(const f32x4*)&s[i * 8];
        f32x4 b = *(const f32x4*)&s[i * 8 + 4];
        short8 o;
        o[0]=(short)f2us(a[0]); o[1]=(short)f2us(a[1]); o[2]=(short)f2us(a[2]); o[3]=(short)f2us(a[3]);
        o[4]=(short)f2us(b[0]); o[5]=(short)f2us(b[1]); o[6]=(short)f2us(b[2]); o[7]=(short)f2us(b[3]);
        *(short8*)&dst[i * 8] = o;
      }
    } else {
      const short8* s = (const short8*)d.src;
      for (int i = tid0; i < n8; i += stride) *(short8*)&dst[i * 8] = s[i];
    }
  } else {
    if (isf32) {
      const float* s = (const float*)d.src;
      for (int i = tid0; i < d.n; i += stride) dst[i] = f2us(s[i]);
    } else {
      const u16* s = (const u16*)d.src;
      for (int i = tid0; i < d.n; i += stride) dst[i] = s[i];
    }
  }
}

// ---------------------------------------------------------------------------
// final pack: staged bf16 outputs -> d_out as bf16 or f32 per flag
// ---------------------------------------------------------------------------
__global__ __launch_bounds__(256) void pack_kernel(const u16* __restrict__ stg,
                                                   void* __restrict__ out, int n8,
                                                   const int* __restrict__ flag)
{
  const int isf32 = flag[0];
  const int stride = gridDim.x * 256;
  for (int i = blockIdx.x * 256 + threadIdx.x; i < n8; i += stride) {
    short8 v = *(const short8*)&stg[i * 8];
    if (isf32) {
      float* o = (float*)out + i * 8;
      f32x4 a, b;
      a[0]=us2f((u16)v[0]); a[1]=us2f((u16)v[1]); a[2]=us2f((u16)v[2]); a[3]=us2f((u16)v[3]);
      b[0]=us2f((u16)v[4]); b[1]=us2f((u16)v[5]); b[2]=us2f((u16)v[6]); b[3]=us2f((u16)v[7]);
      *(f32x4*)o = a; *(f32x4*)(o + 4) = b;
    } else {
      *(short8*)((u16*)out + i * 8) = v;
    }
  }
}

// ---------------------------------------------------------------------------
// Generic NT GEMM: C = A(M,K) @ Bt(N,K)^T, bf16 in, f32 accum.
// EPI: 0 = bf16 row-major (+bias, opt SiLU)
//      1 = f32  row-major (+bias)
//      2 = bf16 transposed V store: Vt[b][col][t], per-batch ntok rows
//      3 = bf16 scores: v*scale + colAdd[zb*sColb + col]
// ---------------------------------------------------------------------------
template<int BM, int BN, int EPI, int SILU>
__global__ __launch_bounds__(256) void gemm_nt(
    const u16* __restrict__ A, long sAb, long sAh, int lda,
    const u16* __restrict__ Bt, long sBb, long sBh, int ldb,
    const u16* __restrict__ bias,
    void* __restrict__ Cout, long sCb, long sCh, int ldc,
    const float* __restrict__ colAdd, long sColb, float scale,
    int K, int HH, int ntok)
{
  constexpr int BK = 32;
  constexpr int FM = BM / 32;
  constexpr int FN = BN / 32;
  __shared__ __align__(16) u16 As[BM * BK];
  __shared__ __align__(16) u16 Bs[BN * BK];

  const int tid  = threadIdx.x;
  const int lane = tid & 63;
  const int wm = (tid >> 6) >> 1;
  const int wn = (tid >> 6) & 1;
  const int z  = blockIdx.z;
  const int zb = z / HH;
  const int zh = z - zb * HH;
  const long row0 = (long)blockIdx.x * BM;
  const long col0 = (long)blockIdx.y * BN;

  const u16* Ab = A  + zb * sAb + zh * sAh + row0 * (long)lda;
  const u16* Bb = Bt + zb * sBb + zh * sBh + col0 * (long)ldb;

  f32x4 acc[FM][FN];
#pragma unroll
  for (int i = 0; i < FM; ++i)
#pragma unroll
    for (int j = 0; j < FN; ++j)
      acc[i][j] = (f32x4){0.f, 0.f, 0.f, 0.f};

  for (int k0 = 0; k0 < K; k0 += BK) {
    __syncthreads();
    for (int c = tid; c < BM * BK / 8; c += 256) {
      const int r  = c >> 2;
      const int kk = (c & 3) << 3;
      __builtin_amdgcn_global_load_lds(
          (const __attribute__((address_space(1))) uint32_t*)(Ab + (long)r * lda + k0 + kk),
          (__attribute__((address_space(3))) uint32_t*)(As + c * 8), 16, 0, 0);
    }
    for (int c = tid; c < BN * BK / 8; c += 256) {
      const int r  = c >> 2;
      const int kk = (c & 3) << 3;
      __builtin_amdgcn_global_load_lds(
          (const __attribute__((address_space(1))) uint32_t*)(Bb + (long)r * ldb + k0 + kk),
          (__attribute__((address_space(3))) uint32_t*)(Bs + c * 8), 16, 0, 0);
    }
    __syncthreads();

    bf16x8 af[FM], bfv[FN];
#pragma unroll
    for (int i = 0; i < FM; ++i)
      af[i] = *(const bf16x8*)&As[(wm * (BM/2) + i*16 + (lane & 15)) * BK + ((lane >> 4) << 3)];
#pragma unroll
    for (int j = 0; j < FN; ++j)
      bfv[j] = *(const bf16x8*)&Bs[(wn * (BN/2) + j*16 + (lane & 15)) * BK + ((lane >> 4) << 3)];
#pragma unroll
    for (int i = 0; i < FM; ++i)
#pragma unroll
      for (int j = 0; j < FN; ++j)
        acc[i][j] = __builtin_amdgcn_mfma_f32_16x16x32_bf16(af[i], bfv[j], acc[i][j], 0, 0, 0);
  }

  // C/D layout: col=lane&15, row=(lane>>4)*4+r  (m89-verified)
#pragma unroll
  for (int i = 0; i < FM; ++i) {
    const long gr0 = row0 + wm * (BM/2) + i * 16 + ((lane >> 4) << 2);
#pragma unroll
    for (int j = 0; j < FN; ++j) {
      const long gc = col0 + wn * (BN/2) + j * 16 + (lane & 15);
      const float badd = bias ? us2f(bias[gc]) : 0.f;
      if constexpr (EPI == 2) {
        const long bb = gr0 / ntok;
        const long t0 = gr0 - bb * ntok;
        u16* dst = (u16*)Cout + bb * ((long)DM * ntok) + gc * (long)ntok + t0;
        u16x4 pk;
#pragma unroll
        for (int r = 0; r < 4; ++r) pk[r] = f2us(acc[i][j][r] + badd);
        *(u16x4*)dst = pk;
      } else if constexpr (EPI == 3) {
        const float ca = colAdd[(long)zb * sColb + gc];
        u16* Cb = (u16*)Cout + zb * sCb + zh * sCh;
#pragma unroll
        for (int r = 0; r < 4; ++r)
          Cb[(gr0 + r) * (long)ldc + gc] = f2us(acc[i][j][r] * scale + ca);
      } else if constexpr (EPI == 1) {
        float* Cf = (float*)Cout + zb * sCb + zh * sCh;
#pragma unroll
        for (int r = 0; r < 4; ++r) {
          float v = acc[i][j][r] + badd;
          if (SILU) v = v / (1.f + expf(-v));
          Cf[(gr0 + r) * (long)ldc + gc] = v;
        }
      } else {
        u16* Cb = (u16*)Cout + zb * sCb + zh * sCh;
#pragma unroll
        for (int r = 0; r < 4; ++r) {
          float v = acc[i][j][r] + badd;
          if (SILU) v = v / (1.f + expf(-v));
          Cb[(gr0 + r) * (long)ldc + gc] = f2us(v);
        }
      }
    }
  }
}

// ---------------------------------------------------------------------------
__global__ __launch_bounds__(256) void transpose_kernel(
    const u16* __restrict__ in, u16* __restrict__ out, int R, int C)
{
  __shared__ u16 t[32][33];
  const int c0 = blockIdx.x * 32, r0 = blockIdx.y * 32;
  const int tx = threadIdx.x & 31, ty = threadIdx.x >> 5;
#pragma unroll
  for (int i = 0; i < 4; ++i)
    t[ty + 8*i][tx] = in[(long)(r0 + ty + 8*i) * C + c0 + tx];
  __syncthreads();
#pragma unroll
  for (int i = 0; i < 4; ++i)
    out[(long)(c0 + ty + 8*i) * R + r0 + tx] = t[tx][ty + 8*i];
}

// ---------------------------------------------------------------------------
template<int CPL>
__global__ __launch_bounds__(256) void softmax_kernel(u16* __restrict__ S)
{
  const long row = (long)blockIdx.x * 4 + (threadIdx.x >> 6);
  const int lane = threadIdx.x & 63;
  u16* r = S + row * (CPL * 64);
  float v[CPL];
  float m = -1e30f;
#pragma unroll
  for (int i = 0; i < CPL; ++i) { v[i] = us2f(r[i*64 + lane]); m = fmaxf(m, v[i]); }
#pragma unroll
  for (int o = 32; o; o >>= 1) m = fmaxf(m, __shfl_xor(m, o));
  float s = 0.f;
#pragma unroll
  for (int i = 0; i < CPL; ++i) { v[i] = expf(v[i] - m); s += v[i]; }
#pragma unroll
  for (int o = 32; o; o >>= 1) s += __shfl_xor(s, o);
  const float inv = 1.f / s;
#pragma unroll
  for (int i = 0; i < CPL; ++i) r[i*64 + lane] = f2us(v[i] * inv);
}

// ---------------------------------------------------------------------------
template<int RES>
__global__ __launch_bounds__(256) void ln_kernel(
    const u16* __restrict__ X, const float* __restrict__ P,
    const u16* __restrict__ g, const u16* __restrict__ bta,
    u16* __restrict__ out, int rows)
{
  const int row = blockIdx.x * 4 + (threadIdx.x >> 6);
  if (row >= rows) return;
  const int lane = threadIdx.x & 63;
  const float* pr = P + (long)row * DM;
  const u16* xr = RES ? (X + (long)row * DM) : nullptr;
  float v[8], s = 0.f, s2 = 0.f;
#pragma unroll
  for (int i = 0; i < 8; ++i) {
    const int jx = i * 64 + lane;
    float t = pr[jx];
    if (RES) t += us2f(xr[jx]);
    v[i] = t; s += t; s2 += t * t;
  }
#pragma unroll
  for (int o = 32; o; o >>= 1) { s += __shfl_xor(s, o); s2 += __shfl_xor(s2, o); }
  const float mean = s * (1.f / DM);
  const float var  = s2 * (1.f / DM) - mean * mean;
  const float rstd = rsqrtf(fmaxf(var, 0.f) + 1e-5f);
  u16* orow = out + (long)row * DM;
#pragma unroll
  for (int i = 0; i < 8; ++i) {
    const int jx = i * 64 + lane;
    orow[jx] = f2us((v[i] - mean) * rstd * us2f(g[jx]) + us2f(bta[jx]));
  }
}

// ---------------------------------------------------------------------------
__global__ __launch_bounds__(256) void evi_gate_kernel(
    const u16* __restrict__ H, const u16* __restrict__ W2, const u16* __restrict__ b2,
    const int* __restrict__ kptr, u16* __restrict__ gout, float* __restrict__ lb, int rows)
{
  const int row = blockIdx.x * 4 + (threadIdx.x >> 6);
  if (row >= rows) return;
  const int lane = threadIdx.x & 63;
  const u16* hr = H + (long)row * DM;
  float p1 = 0.f, p2 = 0.f, p3 = 0.f;
#pragma unroll
  for (int i = 0; i < 8; ++i) {
    const int idx = i * 64 + lane;
    const float hv = us2f(hr[idx]);
    const u16x4 w = *(const u16x4*)&W2[idx * 4];
    p1 += hv * us2f(w[1]);
    p2 += hv * us2f(w[2]); p3 += hv * us2f(w[3]);
  }
#pragma unroll
  for (int o = 32; o; o >>= 1) {
    p1 += __shfl_xor(p1, o);
    p2 += __shfl_xor(p2, o); p3 += __shfl_xor(p3, o);
  }
  if (lane == 0) {
    const float nu = p1 + us2f(b2[1]);
    const float al = p2 + us2f(b2[2]);
    const float be = p3 + us2f(b2[3]);
    auto sp = [](float x) { return x > 20.f ? x : log1pf(expf(x)); };
    const float spn = sp(nu) + 1e-6f;
    const float spa = sp(al);            // alpha - 1
    const float spb = sp(be) + 1e-6f;
    const float sig = spb / (spn * spa);
    const float kk = (float)kptr[0];
    float gg = expf(-kk * sig);
    gg = fminf(fmaxf(gg, 0.05f), 1.f);
    gout[row] = f2us(gg);
    lb[row] = logf(gg + 1e-12f);
  }
}

// ---------------------------------------------------------------------------
extern "C" void kernel_launch(void* const* d_in, const int* in_sizes, int n_in,
                              void* d_out, int out_size, void* d_ws, size_t ws_size,
                              hipStream_t stream)
{
  const int* kptr = (const int*)d_in[2];

  // ---- workspace arena ----
  uint8_t* base = (uint8_t*)d_ws;
  size_t off = 0;
  auto take = [&](size_t bytes) -> void* {
    void* p = base + off;
    off += (bytes + 255) & ~(size_t)255;
    return p;
  };
  int* FLAG = (int*)take(256);

  // canonical bf16 arena for all 42 float tensors (setup_inputs order, skipping k)
  const int sizes[42] = {
    2097152, 8388608,
    262144, 512, 2048, 4,            // evid w1,b1,w2,b2
    262144, 512, 2048, 4,            // evip
    262144,262144,262144,262144, 512,512,512,512, 512,512,   // p2d wq,wk,wv,wo,bq,bk,bv,bo,lng,lnb
    262144,262144,262144,262144, 512,512,512,512, 512,512,   // d2p
    1048576, 2048, 1048576, 512, 512, 512,                   // ffnd w1,b1,w2,b2,lng,lnb
    1048576, 2048, 1048576, 512, 512, 512                    // ffnp
  };
  u16* canon[42];
  u16* cbase = (u16*)take(17319944ul * 2 + 256);
  {
    unsigned long coff = 0;
    for (int i = 0; i < 42; ++i) {
      canon[i] = cbase + coff;
      coff += (unsigned long)((sizes[i] + 7) & ~7);
    }
  }
  const u16 *HdC = canon[0], *HpC = canon[1];
  const u16 *evid_w1 = canon[2], *evid_b1 = canon[3], *evid_w2 = canon[4], *evid_b2 = canon[5];
  const u16 *evip_w1 = canon[6], *evip_b1 = canon[7], *evip_w2 = canon[8], *evip_b2 = canon[9];
  const u16 *p2d_wq = canon[10], *p2d_wk = canon[11], *p2d_wv = canon[12], *p2d_wo = canon[13];
  const u16 *p2d_bq = canon[14], *p2d_bk = canon[15], *p2d_bv = canon[16], *p2d_bo = canon[17];
  const u16 *p2d_lng = canon[18], *p2d_lnb = canon[19];
  const u16 *d2p_wq = canon[20], *d2p_wk = canon[21], *d2p_wv = canon[22], *d2p_wo = canon[23];
  const u16 *d2p_bq = canon[24], *d2p_bk = canon[25], *d2p_bv = canon[26], *d2p_bo = canon[27];
  const u16 *d2p_lng = canon[28], *d2p_lnb = canon[29];
  const u16 *ffnd_w1 = canon[30], *ffnd_b1 = canon[31], *ffnd_w2 = canon[32], *ffnd_b2 = canon[33];
  const u16 *ffnd_lng = canon[34], *ffnd_lnb = canon[35];
  const u16 *ffnp_w1 = canon[36], *ffnp_b1 = canon[37], *ffnp_w2 = canon[38], *ffnp_b2 = canon[39];
  const u16 *ffnp_lng = canon[40], *ffnp_lnb = canon[41];

  u16* evid_w1T = (u16*)take(512*512*2);
  u16* evip_w1T = (u16*)take(512*512*2);
  u16* p2d_wqT = (u16*)take(512*512*2);
  u16* p2d_wkT = (u16*)take(512*512*2);
  u16* p2d_wvT = (u16*)take(512*512*2);
  u16* p2d_woT = (u16*)take(512*512*2);
  u16* d2p_wqT = (u16*)take(512*512*2);
  u16* d2p_wkT = (u16*)take(512*512*2);
  u16* d2p_wvT = (u16*)take(512*512*2);
  u16* d2p_woT = (u16*)take(512*512*2);
  u16* ffnd_w1T = (u16*)take(512*2048*2);
  u16* ffnd_w2T = (u16*)take(2048*512*2);
  u16* ffnp_w1T = (u16*)take(512*2048*2);
  u16* ffnp_w2T = (u16*)take(2048*512*2);
  u16*   SBUF = (u16*)take((size_t)16384*2048*2);    // 64 MiB (scores / ffn h)
  float* PBUF = (float*)take((size_t)16384*512*4);   // f32 pre-LN
  u16*   QBUF = (u16*)take((size_t)16384*512*2);
  u16*   KBUF = (u16*)take((size_t)16384*512*2);
  u16*   VTBUF = (u16*)take((size_t)16384*512*2);
  u16*   ABUF = (u16*)take((size_t)16384*512*2);
  u16*   HP2  = (u16*)take((size_t)16384*512*2);
  u16*   HD2  = (u16*)take((size_t)4096*512*2);
  float* LBD  = (float*)take((size_t)NB*TDr*4);
  float* LBP  = (float*)take((size_t)NB*TPr*4);
  u16*   OSTG = (u16*)take((size_t)10506240*2);      // staged outputs, bf16
  if (off > ws_size) return;

  // staged output offsets (elements)
  const long OS_HD = 0;
  const long OS_HP = 2097152;
  const long OS_GD = 10485760;
  const long OS_GP = 10489856;

  // ---- detect dtype, canonicalize ----
  detect_kernel<<<dim3(1), 64, 0, stream>>>((const u16*)d_in[0], FLAG);
  CvtTable tbl;
  {
    int ii = 0;
    for (int i = 0; i < 43; ++i) {
      if (i == 2) continue;  // k (int)
      tbl.d[ii].src = d_in[i];
      tbl.d[ii].dst_off = (unsigned long)(canon[ii] - cbase);
      tbl.d[ii].n = sizes[ii];
      ++ii;
    }
  }
  cvt_kernel<<<dim3(64, 42), 256, 0, stream>>>(tbl, cbase, FLAG);

  // ---- weight transposes (from canonical) ----
  struct TT { const u16* in; u16* out; int R, C; };
  const TT tts[14] = {
    {evid_w1, evid_w1T, 512, 512}, {evip_w1, evip_w1T, 512, 512},
    {p2d_wq, p2d_wqT, 512, 512}, {p2d_wk, p2d_wkT, 512, 512},
    {p2d_wv, p2d_wvT, 512, 512}, {p2d_wo, p2d_woT, 512, 512},
    {d2p_wq, d2p_wqT, 512, 512}, {d2p_wk, d2p_wkT, 512, 512},
    {d2p_wv, d2p_wvT, 512, 512}, {d2p_wo, d2p_woT, 512, 512},
    {ffnd_w1, ffnd_w1T, 512, 2048}, {ffnd_w2, ffnd_w2T, 2048, 512},
    {ffnp_w1, ffnp_w1T, 512, 2048}, {ffnp_w2, ffnp_w2T, 2048, 512},
  };
  for (int i = 0; i < 14; ++i)
    transpose_kernel<<<dim3(tts[i].C/32, tts[i].R/32), 256, 0, stream>>>(
        tts[i].in, tts[i].out, tts[i].R, tts[i].C);

  const float SCALE = 0.125f;  // 1/sqrt(64)

  // ---- evidential heads ----
  gemm_nt<128,128,0,1><<<dim3(32,4,1),256,0,stream>>>(
      HdC,0,0,512, evid_w1T,0,0,512, evid_b1, QBUF,0,0,512, nullptr,0,0.f, 512,1,0);
  evi_gate_kernel<<<dim3(4096/4),256,0,stream>>>(QBUF, evid_w2, evid_b2, kptr, OSTG + OS_GD, LBD, 4096);
  gemm_nt<128,128,0,1><<<dim3(128,4,1),256,0,stream>>>(
      HpC,0,0,512, evip_w1T,0,0,512, evip_b1, QBUF,0,0,512, nullptr,0,0.f, 512,1,0);
  evi_gate_kernel<<<dim3(16384/4),256,0,stream>>>(QBUF, evip_w2, evip_b2, kptr, OSTG + OS_GP, LBP, 16384);

  // ---- p2d attention: Q=Hp (M=1024/b), KV=Hd (N=256/b), bias=log(gd) ----
  gemm_nt<128,128,0,0><<<dim3(128,4,1),256,0,stream>>>(
      HpC,0,0,512, p2d_wqT,0,0,512, p2d_bq, QBUF,0,0,512, nullptr,0,0.f, 512,1,0);
  gemm_nt<128,128,0,0><<<dim3(32,4,1),256,0,stream>>>(
      HdC,0,0,512, p2d_wkT,0,0,512, p2d_bk, KBUF,0,0,512, nullptr,0,0.f, 512,1,0);
  gemm_nt<128,128,2,0><<<dim3(32,4,1),256,0,stream>>>(
      HdC,0,0,512, p2d_wvT,0,0,512, p2d_bv, VTBUF,0,0,0, nullptr,0,0.f, 512,1,TDr);
  gemm_nt<128,128,3,0><<<dim3(8,2,128),256,0,stream>>>(
      QBUF,(long)TPr*512,64,512, KBUF,(long)TDr*512,64,512, nullptr,
      SBUF,(long)NH*TPr*TDr,(long)TPr*TDr,TDr, LBD,TDr,SCALE, 64,NH,0);
  softmax_kernel<4><<<dim3(NB*NH*TPr/4),256,0,stream>>>(SBUF);
  gemm_nt<128,64,0,0><<<dim3(8,1,128),256,0,stream>>>(
      SBUF,(long)NH*TPr*TDr,(long)TPr*TDr,TDr, VTBUF,(long)DM*TDr,(long)DHEAD*TDr,TDr, nullptr,
      ABUF,(long)TPr*512,64,512, nullptr,0,0.f, TDr,NH,0);
  gemm_nt<128,128,1,0><<<dim3(128,4,1),256,0,stream>>>(
      ABUF,0,0,512, p2d_woT,0,0,512, p2d_bo, PBUF,0,0,512, nullptr,0,0.f, 512,1,0);
  ln_kernel<1><<<dim3(16384/4),256,0,stream>>>(HpC, PBUF, p2d_lng, p2d_lnb, HP2, 16384);

  // ---- d2p attention: Q=Hd (M=256/b), KV=Hp (N=1024/b), bias=log(gp) ----
  gemm_nt<128,128,0,0><<<dim3(32,4,1),256,0,stream>>>(
      HdC,0,0,512, d2p_wqT,0,0,512, d2p_bq, QBUF,0,0,512, nullptr,0,0.f, 512,1,0);
  gemm_nt<128,128,0,0><<<dim3(128,4,1),256,0,stream>>>(
      HpC,0,0,512, d2p_wkT,0,0,512, d2p_bk, KBUF,0,0,512, nullptr,0,0.f, 512,1,0);
  gemm_nt<128,128,2,0><<<dim3(128,4,1),256,0,stream>>>(
      HpC,0,0,512, d2p_wvT,0,0,512, d2p_bv, VTBUF,0,0,0, nullptr,0,0.f, 512,1,TPr);
  gemm_nt<128,128,3,0><<<dim3(2,8,128),256,0,stream>>>(
      QBUF,(long)TDr*512,64,512, KBUF,(long)TPr*512,64,512, nullptr,
      SBUF,(long)NH*TDr*TPr,(long)TDr*TPr,TPr, LBP,TPr,SCALE, 64,NH,0);
  softmax_kernel<16><<<dim3(NB*NH*TDr/4),256,0,stream>>>(SBUF);
  gemm_nt<128,64,0,0><<<dim3(2,1,128),256,0,stream>>>(
      SBUF,(long)NH*TDr*TPr,(long)TDr*TPr,TPr, VTBUF,(long)DM*TPr,(long)DHEAD*TPr,TPr, nullptr,
      ABUF,(long)TDr*512,64,512, nullptr,0,0.f, TPr,NH,0);
  gemm_nt<128,128,1,0><<<dim3(32,4,1),256,0,stream>>>(
      ABUF,0,0,512, d2p_woT,0,0,512, d2p_bo, PBUF,0,0,512, nullptr,0,0.f, 512,1,0);
  ln_kernel<1><<<dim3(4096/4),256,0,stream>>>(HdC, PBUF, d2p_lng, d2p_lnb, HD2, 4096);

  // ---- FFN p ----
  gemm_nt<128,128,0,1><<<dim3(128,16,1),256,0,stream>>>(
      HP2,0,0,512, ffnp_w1T,0,0,512, ffnp_b1, SBUF,0,0,2048, nullptr,0,0.f, 512,1,0);
  gemm_nt<128,128,1,0><<<dim3(128,4,1),256,0,stream>>>(
      SBUF,0,0,2048, ffnp_w2T,0,0,2048, ffnp_b2, PBUF,0,0,512, nullptr,0,0.f, 2048,1,0);
  ln_kernel<0><<<dim3(16384/4),256,0,stream>>>(nullptr, PBUF, ffnp_lng, ffnp_lnb, OSTG + OS_HP, 16384);

  // ---- FFN d ----
  gemm_nt<128,128,0,1><<<dim3(32,16,1),256,0,stream>>>(
      HD2,0,0,512, ffnd_w1T,0,0,512, ffnd_b1, SBUF,0,0,2048, nullptr,0,0.f, 512,1,0);
  gemm_nt<128,128,1,0><<<dim3(32,4,1),256,0,stream>>>(
      SBUF,0,0,2048, ffnd_w2T,0,0,2048, ffnd_b2, PBUF,0,0,512, nullptr,0,0.f, 2048,1,0);
  ln_kernel<0><<<dim3(4096/4),256,0,stream>>>(nullptr, PBUF, ffnd_lng, ffnd_lnb, OSTG + OS_HD, 4096);

  // ---- pack outputs per dtype flag ----
  pack_kernel<<<dim3(1024),256,0,stream>>>(OSTG, d_out, 10506240/8, FLAG);
}

// Round 3
// 640.953 us; speedup vs baseline: 1.0270x; 1.0270x over previous
//
#include <hip/hip_runtime.h>
#include <stdint.h>
#include <math.h>

typedef unsigned short u16;
typedef __attribute__((ext_vector_type(8))) short bf16x8;
typedef __attribute__((ext_vector_type(8))) short short8;
typedef __attribute__((ext_vector_type(4))) float f32x4;
typedef __attribute__((ext_vector_type(4))) unsigned short u16x4;

#define NB 16
#define TDr 256
#define TPr 1024
#define DM 512
#define NH 8
#define DHEAD 64

__device__ __forceinline__ float us2f(u16 u) {
  union { float f; unsigned int i; } x; x.i = ((unsigned int)u) << 16; return x.f;
}
__device__ __forceinline__ u16 f2us(float f) {
  union { float fl; unsigned int i; } x; x.fl = f;
  unsigned int u = x.i;
  return (u16)((u + 0x7fffu + ((u >> 16) & 1u)) >> 16);  // RNE
}

// ---------------------------------------------------------------------------
// dtype detect: if raw u16 stream (bf16 view) contains huge magnitudes, the
// underlying data is f32.
// ---------------------------------------------------------------------------
__global__ __launch_bounds__(64) void detect_kernel(const u16* __restrict__ raw,
                                                    int* __restrict__ flag)
{
  const int lane = threadIdx.x;
  float mx = 0.f;
  for (int i = lane; i < 256; i += 64) {
    float v = us2f(raw[i]);
    v = fabsf(v);
    if (isfinite(v)) mx = fmaxf(mx, v); else mx = 1e30f;
  }
#pragma unroll
  for (int o = 32; o; o >>= 1) mx = fmaxf(mx, __shfl_xor(mx, o));
  if (lane == 0) flag[0] = (mx > 1e10f) ? 1 : 0;
}

// ---------------------------------------------------------------------------
struct CvtDesc { const void* src; unsigned long dst_off; int n; };
struct CvtTable { CvtDesc d[42]; };

__global__ __launch_bounds__(256) void cvt_kernel(CvtTable t, u16* __restrict__ base,
                                                  const int* __restrict__ flag)
{
  const CvtDesc d = t.d[blockIdx.y];
  u16* dst = base + d.dst_off;
  const int isf32 = flag[0];
  const int stride = gridDim.x * 256;
  const int tid0 = blockIdx.x * 256 + threadIdx.x;
  if (d.n >= 8) {
    const int n8 = d.n >> 3;
    if (isf32) {
      const float* s = (const float*)d.src;
      for (int i = tid0; i < n8; i += stride) {
        f32x4 a = *(const f32x4*)&s[i * 8];
        f32x4 b = *(const f32x4*)&s[i * 8 + 4];
        short8 o;
        o[0]=(short)f2us(a[0]); o[1]=(short)f2us(a[1]); o[2]=(short)f2us(a[2]); o[3]=(short)f2us(a[3]);
        o[4]=(short)f2us(b[0]); o[5]=(short)f2us(b[1]); o[6]=(short)f2us(b[2]); o[7]=(short)f2us(b[3]);
        *(short8*)&dst[i * 8] = o;
      }
    } else {
      const short8* s = (const short8*)d.src;
      for (int i = tid0; i < n8; i += stride) *(short8*)&dst[i * 8] = s[i];
    }
  } else {
    if (isf32) {
      const float* s = (const float*)d.src;
      for (int i = tid0; i < d.n; i += stride) dst[i] = f2us(s[i]);
    } else {
      const u16* s = (const u16*)d.src;
      for (int i = tid0; i < d.n; i += stride) dst[i] = s[i];
    }
  }
}

// ---------------------------------------------------------------------------
__global__ __launch_bounds__(256) void pack_kernel(const u16* __restrict__ stg,
                                                   void* __restrict__ out, int n8,
                                                   const int* __restrict__ flag)
{
  const int isf32 = flag[0];
  const int stride = gridDim.x * 256;
  for (int i = blockIdx.x * 256 + threadIdx.x; i < n8; i += stride) {
    short8 v = *(const short8*)&stg[i * 8];
    if (isf32) {
      float* o = (float*)out + i * 8;
      f32x4 a, b;
      a[0]=us2f((u16)v[0]); a[1]=us2f((u16)v[1]); a[2]=us2f((u16)v[2]); a[3]=us2f((u16)v[3]);
      b[0]=us2f((u16)v[4]); b[1]=us2f((u16)v[5]); b[2]=us2f((u16)v[6]); b[3]=us2f((u16)v[7]);
      *(f32x4*)o = a; *(f32x4*)(o + 4) = b;
    } else {
      *(short8*)((u16*)out + i * 8) = v;
    }
  }
}

// ---------------------------------------------------------------------------
// Generic NT GEMM with double-buffered LDS + prefetch (T3 minimum 2-phase):
//   stage(buf0); barrier;
//   loop: stage(buf^1, t+1) -> ds_read+MFMA(buf) -> barrier (drains prefetch)
// EPI: 0 = bf16 row-major (+bias, opt SiLU)
//      1 = f32  row-major (+bias)
//      2 = bf16 transposed V store: Vt[b][col][t], per-batch ntok rows
//      3 = bf16 scores: v*scale + colAdd[zb*sColb + col]
// ---------------------------------------------------------------------------
template<int BM, int BN, int EPI, int SILU>
__global__ __launch_bounds__(256) void gemm_nt(
    const u16* __restrict__ A, long sAb, long sAh, int lda,
    const u16* __restrict__ Bt, long sBb, long sBh, int ldb,
    const u16* __restrict__ bias,
    void* __restrict__ Cout, long sCb, long sCh, int ldc,
    const float* __restrict__ colAdd, long sColb, float scale,
    int K, int HH, int ntok)
{
  constexpr int BK = 32;
  constexpr int FM = BM / 32;
  constexpr int FN = BN / 32;
  __shared__ __align__(16) u16 As[2][BM * BK];
  __shared__ __align__(16) u16 Bs[2][BN * BK];

  const int tid  = threadIdx.x;
  const int lane = tid & 63;
  const int wm = (tid >> 6) >> 1;
  const int wn = (tid >> 6) & 1;
  const int z  = blockIdx.z;
  const int zb = z / HH;
  const int zh = z - zb * HH;
  const long row0 = (long)blockIdx.x * BM;
  const long col0 = (long)blockIdx.y * BN;

  const u16* Ab = A  + zb * sAb + zh * sAh + row0 * (long)lda;
  const u16* Bb = Bt + zb * sBb + zh * sBh + col0 * (long)ldb;

  f32x4 acc[FM][FN];
#pragma unroll
  for (int i = 0; i < FM; ++i)
#pragma unroll
    for (int j = 0; j < FN; ++j)
      acc[i][j] = (f32x4){0.f, 0.f, 0.f, 0.f};

  auto stage = [&](int buf, int k0) {
#pragma unroll
    for (int c = tid; c < BM * BK / 8; c += 256) {
      const int r  = c >> 2;
      const int kk = (c & 3) << 3;
      __builtin_amdgcn_global_load_lds(
          (const __attribute__((address_space(1))) uint32_t*)(Ab + (long)r * lda + k0 + kk),
          (__attribute__((address_space(3))) uint32_t*)(&As[buf][c * 8]), 16, 0, 0);
    }
#pragma unroll
    for (int c = tid; c < BN * BK / 8; c += 256) {
      const int r  = c >> 2;
      const int kk = (c & 3) << 3;
      __builtin_amdgcn_global_load_lds(
          (const __attribute__((address_space(1))) uint32_t*)(Bb + (long)r * ldb + k0 + kk),
          (__attribute__((address_space(3))) uint32_t*)(&Bs[buf][c * 8]), 16, 0, 0);
    }
  };

  const int nt = K / BK;
  int cur = 0;
  stage(0, 0);
  __syncthreads();                 // drain prologue staging

  for (int t = 0; t < nt; ++t) {
    if (t + 1 < nt) stage(cur ^ 1, (t + 1) * BK);   // prefetch next tile (in flight)

    bf16x8 af[FM], bfv[FN];
#pragma unroll
    for (int i = 0; i < FM; ++i)
      af[i] = *(const bf16x8*)&As[cur][(wm * (BM/2) + i*16 + (lane & 15)) * BK + ((lane >> 4) << 3)];
#pragma unroll
    for (int j = 0; j < FN; ++j)
      bfv[j] = *(const bf16x8*)&Bs[cur][(wn * (BN/2) + j*16 + (lane & 15)) * BK + ((lane >> 4) << 3)];
#pragma unroll
    for (int i = 0; i < FM; ++i)
#pragma unroll
      for (int j = 0; j < FN; ++j)
        acc[i][j] = __builtin_amdgcn_mfma_f32_16x16x32_bf16(af[i], bfv[j], acc[i][j], 0, 0, 0);

    __syncthreads();               // drains prefetch vmcnt + LDS-read completion
    cur ^= 1;
  }

  // C/D layout: col=lane&15, row=(lane>>4)*4+r  (m89-verified)
#pragma unroll
  for (int i = 0; i < FM; ++i) {
    const long gr0 = row0 + wm * (BM/2) + i * 16 + ((lane >> 4) << 2);
#pragma unroll
    for (int j = 0; j < FN; ++j) {
      const long gc = col0 + wn * (BN/2) + j * 16 + (lane & 15);
      const float badd = bias ? us2f(bias[gc]) : 0.f;
      if constexpr (EPI == 2) {
        const long bb = gr0 / ntok;
        const long t0 = gr0 - bb * ntok;
        u16* dst = (u16*)Cout + bb * ((long)DM * ntok) + gc * (long)ntok + t0;
        u16x4 pk;
#pragma unroll
        for (int r = 0; r < 4; ++r) pk[r] = f2us(acc[i][j][r] + badd);
        *(u16x4*)dst = pk;
      } else if constexpr (EPI == 3) {
        const float ca = colAdd[(long)zb * sColb + gc];
        u16* Cb = (u16*)Cout + zb * sCb + zh * sCh;
#pragma unroll
        for (int r = 0; r < 4; ++r)
          Cb[(gr0 + r) * (long)ldc + gc] = f2us(acc[i][j][r] * scale + ca);
      } else if constexpr (EPI == 1) {
        float* Cf = (float*)Cout + zb * sCb + zh * sCh;
#pragma unroll
        for (int r = 0; r < 4; ++r) {
          float v = acc[i][j][r] + badd;
          if (SILU) v = v / (1.f + expf(-v));
          Cf[(gr0 + r) * (long)ldc + gc] = v;
        }
      } else {
        u16* Cb = (u16*)Cout + zb * sCb + zh * sCh;
#pragma unroll
        for (int r = 0; r < 4; ++r) {
          float v = acc[i][j][r] + badd;
          if (SILU) v = v / (1.f + expf(-v));
          Cb[(gr0 + r) * (long)ldc + gc] = f2us(v);
        }
      }
    }
  }
}

// ---------------------------------------------------------------------------
// batched bf16 transpose: one launch, z picks the tensor
// ---------------------------------------------------------------------------
struct TTab { const u16* in; u16* out; int R, C; };
struct TTable { TTab d[14]; };

__global__ __launch_bounds__(256) void transpose_all(TTable tt)
{
  const TTab d = tt.d[blockIdx.z];
  __shared__ u16 t[32][33];
  const int tx = threadIdx.x & 31, ty = threadIdx.x >> 5;
  for (int r0 = blockIdx.y * 32; r0 < d.R; r0 += gridDim.y * 32) {
    for (int c0 = blockIdx.x * 32; c0 < d.C; c0 += gridDim.x * 32) {
#pragma unroll
      for (int i = 0; i < 4; ++i)
        t[ty + 8*i][tx] = d.in[(long)(r0 + ty + 8*i) * d.C + c0 + tx];
      __syncthreads();
#pragma unroll
      for (int i = 0; i < 4; ++i)
        d.out[(long)(c0 + ty + 8*i) * d.R + r0 + tx] = t[tx][ty + 8*i];
      __syncthreads();
    }
  }
}

// ---------------------------------------------------------------------------
template<int CPL>
__global__ __launch_bounds__(256) void softmax_kernel(u16* __restrict__ S)
{
  const long row = (long)blockIdx.x * 4 + (threadIdx.x >> 6);
  const int lane = threadIdx.x & 63;
  u16* r = S + row * (CPL * 64);
  float v[CPL];
  float m = -1e30f;
#pragma unroll
  for (int i = 0; i < CPL; ++i) { v[i] = us2f(r[i*64 + lane]); m = fmaxf(m, v[i]); }
#pragma unroll
  for (int o = 32; o; o >>= 1) m = fmaxf(m, __shfl_xor(m, o));
  float s = 0.f;
#pragma unroll
  for (int i = 0; i < CPL; ++i) { v[i] = expf(v[i] - m); s += v[i]; }
#pragma unroll
  for (int o = 32; o; o >>= 1) s += __shfl_xor(s, o);
  const float inv = 1.f / s;
#pragma unroll
  for (int i = 0; i < CPL; ++i) r[i*64 + lane] = f2us(v[i] * inv);
}

// ---------------------------------------------------------------------------
template<int RES>
__global__ __launch_bounds__(256) void ln_kernel(
    const u16* __restrict__ X, const float* __restrict__ P,
    const u16* __restrict__ g, const u16* __restrict__ bta,
    u16* __restrict__ out, int rows)
{
  const int row = blockIdx.x * 4 + (threadIdx.x >> 6);
  if (row >= rows) return;
  const int lane = threadIdx.x & 63;
  const float* pr = P + (long)row * DM;
  const u16* xr = RES ? (X + (long)row * DM) : nullptr;
  float v[8], s = 0.f, s2 = 0.f;
#pragma unroll
  for (int i = 0; i < 8; ++i) {
    const int jx = i * 64 + lane;
    float t = pr[jx];
    if (RES) t += us2f(xr[jx]);
    v[i] = t; s += t; s2 += t * t;
  }
#pragma unroll
  for (int o = 32; o; o >>= 1) { s += __shfl_xor(s, o); s2 += __shfl_xor(s2, o); }
  const float mean = s * (1.f / DM);
  const float var  = s2 * (1.f / DM) - mean * mean;
  const float rstd = rsqrtf(fmaxf(var, 0.f) + 1e-5f);
  u16* orow = out + (long)row * DM;
#pragma unroll
  for (int i = 0; i < 8; ++i) {
    const int jx = i * 64 + lane;
    orow[jx] = f2us((v[i] - mean) * rstd * us2f(g[jx]) + us2f(bta[jx]));
  }
}

// ---------------------------------------------------------------------------
__global__ __launch_bounds__(256) void evi_gate_kernel(
    const u16* __restrict__ H, const u16* __restrict__ W2, const u16* __restrict__ b2,
    const int* __restrict__ kptr, u16* __restrict__ gout, float* __restrict__ lb, int rows)
{
  const int row = blockIdx.x * 4 + (threadIdx.x >> 6);
  if (row >= rows) return;
  const int lane = threadIdx.x & 63;
  const u16* hr = H + (long)row * DM;
  float p1 = 0.f, p2 = 0.f, p3 = 0.f;
#pragma unroll
  for (int i = 0; i < 8; ++i) {
    const int idx = i * 64 + lane;
    const float hv = us2f(hr[idx]);
    const u16x4 w = *(const u16x4*)&W2[idx * 4];
    p1 += hv * us2f(w[1]);
    p2 += hv * us2f(w[2]); p3 += hv * us2f(w[3]);
  }
#pragma unroll
  for (int o = 32; o; o >>= 1) {
    p1 += __shfl_xor(p1, o);
    p2 += __shfl_xor(p2, o); p3 += __shfl_xor(p3, o);
  }
  if (lane == 0) {
    const float nu = p1 + us2f(b2[1]);
    const float al = p2 + us2f(b2[2]);
    const float be = p3 + us2f(b2[3]);
    auto sp = [](float x) { return x > 20.f ? x : log1pf(expf(x)); };
    const float spn = sp(nu) + 1e-6f;
    const float spa = sp(al);            // alpha - 1
    const float spb = sp(be) + 1e-6f;
    const float sig = spb / (spn * spa);
    const float kk = (float)kptr[0];
    float gg = expf(-kk * sig);
    gg = fminf(fmaxf(gg, 0.05f), 1.f);
    gout[row] = f2us(gg);
    lb[row] = logf(gg + 1e-12f);
  }
}

// ---------------------------------------------------------------------------
extern "C" void kernel_launch(void* const* d_in, const int* in_sizes, int n_in,
                              void* d_out, int out_size, void* d_ws, size_t ws_size,
                              hipStream_t stream)
{
  const int* kptr = (const int*)d_in[2];

  // ---- workspace arena ----
  uint8_t* base = (uint8_t*)d_ws;
  size_t off = 0;
  auto take = [&](size_t bytes) -> void* {
    void* p = base + off;
    off += (bytes + 255) & ~(size_t)255;
    return p;
  };
  int* FLAG = (int*)take(256);

  const int sizes[42] = {
    2097152, 8388608,
    262144, 512, 2048, 4,
    262144, 512, 2048, 4,
    262144,262144,262144,262144, 512,512,512,512, 512,512,
    262144,262144,262144,262144, 512,512,512,512, 512,512,
    1048576, 2048, 1048576, 512, 512, 512,
    1048576, 2048, 1048576, 512, 512, 512
  };
  u16* canon[42];
  u16* cbase = (u16*)take(17319944ul * 2 + 256);
  {
    unsigned long coff = 0;
    for (int i = 0; i < 42; ++i) {
      canon[i] = cbase + coff;
      coff += (unsigned long)((sizes[i] + 7) & ~7);
    }
  }
  const u16 *HdC = canon[0], *HpC = canon[1];
  const u16 *evid_w1 = canon[2], *evid_b1 = canon[3], *evid_w2 = canon[4], *evid_b2 = canon[5];
  const u16 *evip_w1 = canon[6], *evip_b1 = canon[7], *evip_w2 = canon[8], *evip_b2 = canon[9];
  const u16 *p2d_wq = canon[10], *p2d_wk = canon[11], *p2d_wv = canon[12], *p2d_wo = canon[13];
  const u16 *p2d_bq = canon[14], *p2d_bk = canon[15], *p2d_bv = canon[16], *p2d_bo = canon[17];
  const u16 *p2d_lng = canon[18], *p2d_lnb = canon[19];
  const u16 *d2p_wq = canon[20], *d2p_wk = canon[21], *d2p_wv = canon[22], *d2p_wo = canon[23];
  const u16 *d2p_bq = canon[24], *d2p_bk = canon[25], *d2p_bv = canon[26], *d2p_bo = canon[27];
  const u16 *d2p_lng = canon[28], *d2p_lnb = canon[29];
  const u16 *ffnd_w1 = canon[30], *ffnd_b1 = canon[31], *ffnd_w2 = canon[32], *ffnd_b2 = canon[33];
  const u16 *ffnd_lng = canon[34], *ffnd_lnb = canon[35];
  const u16 *ffnp_w1 = canon[36], *ffnp_b1 = canon[37], *ffnp_w2 = canon[38], *ffnp_b2 = canon[39];
  const u16 *ffnp_lng = canon[40], *ffnp_lnb = canon[41];

  u16* evid_w1T = (u16*)take(512*512*2);
  u16* evip_w1T = (u16*)take(512*512*2);
  u16* p2d_wqT = (u16*)take(512*512*2);
  u16* p2d_wkT = (u16*)take(512*512*2);
  u16* p2d_wvT = (u16*)take(512*512*2);
  u16* p2d_woT = (u16*)take(512*512*2);
  u16* d2p_wqT = (u16*)take(512*512*2);
  u16* d2p_wkT = (u16*)take(512*512*2);
  u16* d2p_wvT = (u16*)take(512*512*2);
  u16* d2p_woT = (u16*)take(512*512*2);
  u16* ffnd_w1T = (u16*)take(512*2048*2);
  u16* ffnd_w2T = (u16*)take(2048*512*2);
  u16* ffnp_w1T = (u16*)take(512*2048*2);
  u16* ffnp_w2T = (u16*)take(2048*512*2);
  u16*   SBUF = (u16*)take((size_t)16384*2048*2);
  float* PBUF = (float*)take((size_t)16384*512*4);
  u16*   QBUF = (u16*)take((size_t)16384*512*2);
  u16*   KBUF = (u16*)take((size_t)16384*512*2);
  u16*   VTBUF = (u16*)take((size_t)16384*512*2);
  u16*   ABUF = (u16*)take((size_t)16384*512*2);
  u16*   HP2  = (u16*)take((size_t)16384*512*2);
  u16*   HD2  = (u16*)take((size_t)4096*512*2);
  float* LBD  = (float*)take((size_t)NB*TDr*4);
  float* LBP  = (float*)take((size_t)NB*TPr*4);
  u16*   OSTG = (u16*)take((size_t)10506240*2);
  if (off > ws_size) return;

  const long OS_HD = 0;
  const long OS_HP = 2097152;
  const long OS_GD = 10485760;
  const long OS_GP = 10489856;

  // ---- detect dtype, canonicalize ----
  detect_kernel<<<dim3(1), 64, 0, stream>>>((const u16*)d_in[0], FLAG);
  CvtTable tbl;
  {
    int ii = 0;
    for (int i = 0; i < 43; ++i) {
      if (i == 2) continue;
      tbl.d[ii].src = d_in[i];
      tbl.d[ii].dst_off = (unsigned long)(canon[ii] - cbase);
      tbl.d[ii].n = sizes[ii];
      ++ii;
    }
  }
  cvt_kernel<<<dim3(64, 42), 256, 0, stream>>>(tbl, cbase, FLAG);

  // ---- weight transposes (one launch) ----
  TTable tt;
  {
    const TTab tts[14] = {
      {evid_w1, evid_w1T, 512, 512}, {evip_w1, evip_w1T, 512, 512},
      {p2d_wq, p2d_wqT, 512, 512}, {p2d_wk, p2d_wkT, 512, 512},
      {p2d_wv, p2d_wvT, 512, 512}, {p2d_wo, p2d_woT, 512, 512},
      {d2p_wq, d2p_wqT, 512, 512}, {d2p_wk, d2p_wkT, 512, 512},
      {d2p_wv, d2p_wvT, 512, 512}, {d2p_wo, d2p_woT, 512, 512},
      {ffnd_w1, ffnd_w1T, 512, 2048}, {ffnd_w2, ffnd_w2T, 2048, 512},
      {ffnp_w1, ffnp_w1T, 512, 2048}, {ffnp_w2, ffnp_w2T, 2048, 512},
    };
    for (int i = 0; i < 14; ++i) tt.d[i] = tts[i];
  }
  transpose_all<<<dim3(16, 16, 14), 256, 0, stream>>>(tt);

  const float SCALE = 0.125f;  // 1/sqrt(64)

  // ---- evidential heads ----
  gemm_nt<128,128,0,1><<<dim3(32,4,1),256,0,stream>>>(
      HdC,0,0,512, evid_w1T,0,0,512, evid_b1, QBUF,0,0,512, nullptr,0,0.f, 512,1,0);
  evi_gate_kernel<<<dim3(4096/4),256,0,stream>>>(QBUF, evid_w2, evid_b2, kptr, OSTG + OS_GD, LBD, 4096);
  gemm_nt<128,128,0,1><<<dim3(128,4,1),256,0,stream>>>(
      HpC,0,0,512, evip_w1T,0,0,512, evip_b1, QBUF,0,0,512, nullptr,0,0.f, 512,1,0);
  evi_gate_kernel<<<dim3(16384/4),256,0,stream>>>(QBUF, evip_w2, evip_b2, kptr, OSTG + OS_GP, LBP, 16384);

  // ---- p2d attention: Q=Hp (M=1024/b), KV=Hd (N=256/b), bias=log(gd) ----
  gemm_nt<128,128,0,0><<<dim3(128,4,1),256,0,stream>>>(
      HpC,0,0,512, p2d_wqT,0,0,512, p2d_bq, QBUF,0,0,512, nullptr,0,0.f, 512,1,0);
  gemm_nt<128,128,0,0><<<dim3(32,4,1),256,0,stream>>>(
      HdC,0,0,512, p2d_wkT,0,0,512, p2d_bk, KBUF,0,0,512, nullptr,0,0.f, 512,1,0);
  gemm_nt<128,128,2,0><<<dim3(32,4,1),256,0,stream>>>(
      HdC,0,0,512, p2d_wvT,0,0,512, p2d_bv, VTBUF,0,0,0, nullptr,0,0.f, 512,1,TDr);
  gemm_nt<128,128,3,0><<<dim3(8,2,128),256,0,stream>>>(
      QBUF,(long)TPr*512,64,512, KBUF,(long)TDr*512,64,512, nullptr,
      SBUF,(long)NH*TPr*TDr,(long)TPr*TDr,TDr, LBD,TDr,SCALE, 64,NH,0);
  softmax_kernel<4><<<dim3(NB*NH*TPr/4),256,0,stream>>>(SBUF);
  gemm_nt<128,64,0,0><<<dim3(8,1,128),256,0,stream>>>(
      SBUF,(long)NH*TPr*TDr,(long)TPr*TDr,TDr, VTBUF,(long)DM*TDr,(long)DHEAD*TDr,TDr, nullptr,
      ABUF,(long)TPr*512,64,512, nullptr,0,0.f, TDr,NH,0);
  gemm_nt<128,128,1,0><<<dim3(128,4,1),256,0,stream>>>(
      ABUF,0,0,512, p2d_woT,0,0,512, p2d_bo, PBUF,0,0,512, nullptr,0,0.f, 512,1,0);
  ln_kernel<1><<<dim3(16384/4),256,0,stream>>>(HpC, PBUF, p2d_lng, p2d_lnb, HP2, 16384);

  // ---- d2p attention: Q=Hd (M=256/b), KV=Hp (N=1024/b), bias=log(gp) ----
  gemm_nt<128,128,0,0><<<dim3(32,4,1),256,0,stream>>>(
      HdC,0,0,512, d2p_wqT,0,0,512, d2p_bq, QBUF,0,0,512, nullptr,0,0.f, 512,1,0);
  gemm_nt<128,128,0,0><<<dim3(128,4,1),256,0,stream>>>(
      HpC,0,0,512, d2p_wkT,0,0,512, d2p_bk, KBUF,0,0,512, nullptr,0,0.f, 512,1,0);
  gemm_nt<128,128,2,0><<<dim3(128,4,1),256,0,stream>>>(
      HpC,0,0,512, d2p_wvT,0,0,512, d2p_bv, VTBUF,0,0,0, nullptr,0,0.f, 512,1,TPr);
  gemm_nt<128,128,3,0><<<dim3(2,8,128),256,0,stream>>>(
      QBUF,(long)TDr*512,64,512, KBUF,(long)TPr*512,64,512, nullptr,
      SBUF,(long)NH*TDr*TPr,(long)TDr*TPr,TPr, LBP,TPr,SCALE, 64,NH,0);
  softmax_kernel<16><<<dim3(NB*NH*TDr/4),256,0,stream>>>(SBUF);
  gemm_nt<128,64,0,0><<<dim3(2,1,128),256,0,stream>>>(
      SBUF,(long)NH*TDr*TPr,(long)TDr*TPr,TPr, VTBUF,(long)DM*TPr,(long)DHEAD*TPr,TPr, nullptr,
      ABUF,(long)TDr*512,64,512, nullptr,0,0.f, TPr,NH,0);
  gemm_nt<128,128,1,0><<<dim3(32,4,1),256,0,stream>>>(
      ABUF,0,0,512, d2p_woT,0,0,512, d2p_bo, PBUF,0,0,512, nullptr,0,0.f, 512,1,0);
  ln_kernel<1><<<dim3(4096/4),256,0,stream>>>(HdC, PBUF, d2p_lng, d2p_lnb, HD2, 4096);

  // ---- FFN p ----
  gemm_nt<128,128,0,1><<<dim3(128,16,1),256,0,stream>>>(
      HP2,0,0,512, ffnp_w1T,0,0,512, ffnp_b1, SBUF,0,0,2048, nullptr,0,0.f, 512,1,0);
  gemm_nt<128,128,1,0><<<dim3(128,4,1),256,0,stream>>>(
      SBUF,0,0,2048, ffnp_w2T,0,0,2048, ffnp_b2, PBUF,0,0,512, nullptr,0,0.f, 2048,1,0);
  ln_kernel<0><<<dim3(16384/4),256,0,stream>>>(nullptr, PBUF, ffnp_lng, ffnp_lnb, OSTG + OS_HP, 16384);

  // ---- FFN d ----
  gemm_nt<128,128,0,1><<<dim3(32,16,1),256,0,stream>>>(
      HD2,0,0,512, ffnd_w1T,0,0,512, ffnd_b1, SBUF,0,0,2048, nullptr,0,0.f, 512,1,0);
  gemm_nt<128,128,1,0><<<dim3(32,4,1),256,0,stream>>>(
      SBUF,0,0,2048, ffnd_w2T,0,0,2048, ffnd_b2, PBUF,0,0,512, nullptr,0,0.f, 2048,1,0);
  ln_kernel<0><<<dim3(4096/4),256,0,stream>>>(nullptr, PBUF, ffnd_lng, ffnd_lnb, OSTG + OS_HD, 4096);

  // ---- pack outputs per dtype flag ----
  pack_kernel<<<dim3(1024),256,0,stream>>>(OSTG, d_out, 10506240/8, FLAG);
}

// Round 4
// 607.550 us; speedup vs baseline: 1.0834x; 1.0550x over previous
//
#include <hip/hip_runtime.h>
#include <stdint.h>
#include <math.h>

typedef unsigned short u16;
typedef __attribute__((ext_vector_type(8))) short bf16x8;
typedef __attribute__((ext_vector_type(8))) short short8;
typedef __attribute__((ext_vector_type(4))) float f32x4;
typedef __attribute__((ext_vector_type(4))) unsigned short u16x4;

#define NB 16
#define TDr 256
#define TPr 1024
#define DM 512
#define NH 8
#define DHEAD 64

__device__ __forceinline__ float us2f(u16 u) {
  union { float f; unsigned int i; } x; x.i = ((unsigned int)u) << 16; return x.f;
}
__device__ __forceinline__ u16 f2us(float f) {
  union { float fl; unsigned int i; } x; x.fl = f;
  unsigned int u = x.i;
  return (u16)((u + 0x7fffu + ((u >> 16) & 1u)) >> 16);  // RNE
}

// ---------------------------------------------------------------------------
__global__ __launch_bounds__(64) void detect_kernel(const u16* __restrict__ raw,
                                                    int* __restrict__ flag)
{
  const int lane = threadIdx.x;
  float mx = 0.f;
  for (int i = lane; i < 256; i += 64) {
    float v = us2f(raw[i]);
    v = fabsf(v);
    if (isfinite(v)) mx = fmaxf(mx, v); else mx = 1e30f;
  }
#pragma unroll
  for (int o = 32; o; o >>= 1) mx = fmaxf(mx, __shfl_xor(mx, o));
  if (lane == 0) flag[0] = (mx > 1e10f) ? 1 : 0;
}

// ---------------------------------------------------------------------------
struct CvtDesc { const void* src; unsigned long dst_off; int n; };
struct CvtTable { CvtDesc d[42]; };

__global__ __launch_bounds__(256) void cvt_kernel(CvtTable t, u16* __restrict__ base,
                                                  const int* __restrict__ flag)
{
  const CvtDesc d = t.d[blockIdx.y];
  u16* dst = base + d.dst_off;
  const int isf32 = flag[0];
  const int stride = gridDim.x * 256;
  const int tid0 = blockIdx.x * 256 + threadIdx.x;
  if (d.n >= 8) {
    const int n8 = d.n >> 3;
    if (isf32) {
      const float* s = (const float*)d.src;
      for (int i = tid0; i < n8; i += stride) {
        f32x4 a = *(const f32x4*)&s[i * 8];
        f32x4 b = *(const f32x4*)&s[i * 8 + 4];
        short8 o;
        o[0]=(short)f2us(a[0]); o[1]=(short)f2us(a[1]); o[2]=(short)f2us(a[2]); o[3]=(short)f2us(a[3]);
        o[4]=(short)f2us(b[0]); o[5]=(short)f2us(b[1]); o[6]=(short)f2us(b[2]); o[7]=(short)f2us(b[3]);
        *(short8*)&dst[i * 8] = o;
      }
    } else {
      const short8* s = (const short8*)d.src;
      for (int i = tid0; i < n8; i += stride) *(short8*)&dst[i * 8] = s[i];
    }
  } else {
    if (isf32) {
      const float* s = (const float*)d.src;
      for (int i = tid0; i < d.n; i += stride) dst[i] = f2us(s[i]);
    } else {
      const u16* s = (const u16*)d.src;
      for (int i = tid0; i < d.n; i += stride) dst[i] = s[i];
    }
  }
}

// ---------------------------------------------------------------------------
__global__ __launch_bounds__(256) void pack_kernel(const u16* __restrict__ stg,
                                                   void* __restrict__ out, int n8,
                                                   const int* __restrict__ flag)
{
  const int isf32 = flag[0];
  const int stride = gridDim.x * 256;
  for (int i = blockIdx.x * 256 + threadIdx.x; i < n8; i += stride) {
    short8 v = *(const short8*)&stg[i * 8];
    if (isf32) {
      float* o = (float*)out + i * 8;
      f32x4 a, b;
      a[0]=us2f((u16)v[0]); a[1]=us2f((u16)v[1]); a[2]=us2f((u16)v[2]); a[3]=us2f((u16)v[3]);
      b[0]=us2f((u16)v[4]); b[1]=us2f((u16)v[5]); b[2]=us2f((u16)v[6]); b[3]=us2f((u16)v[7]);
      *(f32x4*)o = a; *(f32x4*)(o + 4) = b;
    } else {
      *(short8*)((u16*)out + i * 8) = v;
    }
  }
}

// ---------------------------------------------------------------------------
// NT GEMM with 2-deep global_load_lds pipeline and COUNTED vmcnt (T3+T4):
// loads for tile t+1 stay in flight across the barrier; never drain to 0
// in the main loop.
// EPI: 0 bf16 (+bias, opt SiLU) | 1 f32 (+bias) | 2 bf16 V^T store | 3 scores
// ---------------------------------------------------------------------------
template<int BM, int BN, int EPI, int SILU>
__global__ __launch_bounds__(256) void gemm_nt(
    const u16* __restrict__ A, long sAb, long sAh, int lda,
    const u16* __restrict__ Bt, long sBb, long sBh, int ldb,
    const u16* __restrict__ bias,
    void* __restrict__ Cout, long sCb, long sCh, int ldc,
    const float* __restrict__ colAdd, long sColb, float scale,
    int K, int HH, int ntok)
{
  constexpr int BK = 32;
  constexpr int FM = BM / 32;
  constexpr int FN = BN / 32;
  constexpr int LPT = (BM * BK / 8 + BN * BK / 8) / 256;  // loads/thread/tile
  __shared__ __align__(16) u16 As[2][BM * BK];
  __shared__ __align__(16) u16 Bs[2][BN * BK];

  const int tid  = threadIdx.x;
  const int lane = tid & 63;
  const int wm = (tid >> 6) >> 1;
  const int wn = (tid >> 6) & 1;
  const int z  = blockIdx.z;
  const int zb = z / HH;
  const int zh = z - zb * HH;
  const long row0 = (long)blockIdx.x * BM;
  const long col0 = (long)blockIdx.y * BN;

  const u16* Ab = A  + zb * sAb + zh * sAh + row0 * (long)lda;
  const u16* Bb = Bt + zb * sBb + zh * sBh + col0 * (long)ldb;

  f32x4 acc[FM][FN];
#pragma unroll
  for (int i = 0; i < FM; ++i)
#pragma unroll
    for (int j = 0; j < FN; ++j)
      acc[i][j] = (f32x4){0.f, 0.f, 0.f, 0.f};

  auto stage = [&](int buf, int k0) {
#pragma unroll
    for (int c = tid; c < BM * BK / 8; c += 256) {
      const int r  = c >> 2;
      const int kk = (c & 3) << 3;
      __builtin_amdgcn_global_load_lds(
          (const __attribute__((address_space(1))) uint32_t*)(Ab + (long)r * lda + k0 + kk),
          (__attribute__((address_space(3))) uint32_t*)(&As[buf][c * 8]), 16, 0, 0);
    }
#pragma unroll
    for (int c = tid; c < BN * BK / 8; c += 256) {
      const int r  = c >> 2;
      const int kk = (c & 3) << 3;
      __builtin_amdgcn_global_load_lds(
          (const __attribute__((address_space(1))) uint32_t*)(Bb + (long)r * ldb + k0 + kk),
          (__attribute__((address_space(3))) uint32_t*)(&Bs[buf][c * 8]), 16, 0, 0);
    }
  };

  const int nt = K / BK;
  stage(0, 0);
  if (nt > 1) stage(1, BK);

  for (int t = 0; t < nt; ++t) {
    // wait ONLY for tile t's loads; tile t+1's stay in flight (T4)
    if (t + 1 < nt) {
      if constexpr (LPT == 4) asm volatile("s_waitcnt vmcnt(4)" ::: "memory");
      else                    asm volatile("s_waitcnt vmcnt(3)" ::: "memory");
    } else {
      asm volatile("s_waitcnt vmcnt(0)" ::: "memory");
    }
    asm volatile("s_barrier" ::: "memory");     // tile t visible to all waves
    __builtin_amdgcn_sched_barrier(0);

    const int cur = t & 1;
    bf16x8 af[FM], bfv[FN];
#pragma unroll
    for (int i = 0; i < FM; ++i)
      af[i] = *(const bf16x8*)&As[cur][(wm * (BM/2) + i*16 + (lane & 15)) * BK + ((lane >> 4) << 3)];
#pragma unroll
    for (int j = 0; j < FN; ++j)
      bfv[j] = *(const bf16x8*)&Bs[cur][(wn * (BN/2) + j*16 + (lane & 15)) * BK + ((lane >> 4) << 3)];
#pragma unroll
    for (int i = 0; i < FM; ++i)
#pragma unroll
      for (int j = 0; j < FN; ++j)
        acc[i][j] = __builtin_amdgcn_mfma_f32_16x16x32_bf16(af[i], bfv[j], acc[i][j], 0, 0, 0);

    __builtin_amdgcn_sched_barrier(0);
    asm volatile("s_barrier" ::: "memory");     // all waves done reading buf[cur]
    __builtin_amdgcn_sched_barrier(0);
    if (t + 2 < nt) stage(cur, (t + 2) * BK);   // refill freed buffer
  }

  // C/D layout: col=lane&15, row=(lane>>4)*4+r  (m89-verified)
#pragma unroll
  for (int i = 0; i < FM; ++i) {
    const long gr0 = row0 + wm * (BM/2) + i * 16 + ((lane >> 4) << 2);
#pragma unroll
    for (int j = 0; j < FN; ++j) {
      const long gc = col0 + wn * (BN/2) + j * 16 + (lane & 15);
      const float badd = bias ? us2f(bias[gc]) : 0.f;
      if constexpr (EPI == 2) {
        const long bb = gr0 / ntok;
        const long t0 = gr0 - bb * ntok;
        u16* dst = (u16*)Cout + bb * ((long)DM * ntok) + gc * (long)ntok + t0;
        u16x4 pk;
#pragma unroll
        for (int r = 0; r < 4; ++r) pk[r] = f2us(acc[i][j][r] + badd);
        *(u16x4*)dst = pk;
      } else if constexpr (EPI == 3) {
        const float ca = colAdd[(long)zb * sColb + gc];
        u16* Cb = (u16*)Cout + zb * sCb + zh * sCh;
#pragma unroll
        for (int r = 0; r < 4; ++r)
          Cb[(gr0 + r) * (long)ldc + gc] = f2us(acc[i][j][r] * scale + ca);
      } else if constexpr (EPI == 1) {
        float* Cf = (float*)Cout + zb * sCb + zh * sCh;
#pragma unroll
        for (int r = 0; r < 4; ++r) {
          float v = acc[i][j][r] + badd;
          if (SILU) v = v / (1.f + __expf(-v));
          Cf[(gr0 + r) * (long)ldc + gc] = v;
        }
      } else {
        u16* Cb = (u16*)Cout + zb * sCb + zh * sCh;
#pragma unroll
        for (int r = 0; r < 4; ++r) {
          float v = acc[i][j][r] + badd;
          if (SILU) v = v / (1.f + __expf(-v));
          Cb[(gr0 + r) * (long)ldc + gc] = f2us(v);
        }
      }
    }
  }
}

// ---------------------------------------------------------------------------
struct TTab { const u16* in; u16* out; int R, C; };
struct TTable { TTab d[14]; };

__global__ __launch_bounds__(256) void transpose_all(TTable tt)
{
  const TTab d = tt.d[blockIdx.z];
  __shared__ u16 t[32][33];
  const int tx = threadIdx.x & 31, ty = threadIdx.x >> 5;
  for (int r0 = blockIdx.y * 32; r0 < d.R; r0 += gridDim.y * 32) {
    for (int c0 = blockIdx.x * 32; c0 < d.C; c0 += gridDim.x * 32) {
#pragma unroll
      for (int i = 0; i < 4; ++i)
        t[ty + 8*i][tx] = d.in[(long)(r0 + ty + 8*i) * d.C + c0 + tx];
      __syncthreads();
#pragma unroll
      for (int i = 0; i < 4; ++i)
        d.out[(long)(c0 + ty + 8*i) * d.R + r0 + tx] = t[tx][ty + 8*i];
      __syncthreads();
    }
  }
}

// ---------------------------------------------------------------------------
template<int CPL>
__global__ __launch_bounds__(256) void softmax_kernel(u16* __restrict__ S)
{
  const long row = (long)blockIdx.x * 4 + (threadIdx.x >> 6);
  const int lane = threadIdx.x & 63;
  u16* r = S + row * (CPL * 64);
  float v[CPL];
  float m = -1e30f;
#pragma unroll
  for (int i = 0; i < CPL; ++i) { v[i] = us2f(r[i*64 + lane]); m = fmaxf(m, v[i]); }
#pragma unroll
  for (int o = 32; o; o >>= 1) m = fmaxf(m, __shfl_xor(m, o));
  float s = 0.f;
#pragma unroll
  for (int i = 0; i < CPL; ++i) { v[i] = __expf(v[i] - m); s += v[i]; }
#pragma unroll
  for (int o = 32; o; o >>= 1) s += __shfl_xor(s, o);
  const float inv = 1.f / s;
#pragma unroll
  for (int i = 0; i < CPL; ++i) r[i*64 + lane] = f2us(v[i] * inv);
}

// ---------------------------------------------------------------------------
template<int RES>
__global__ __launch_bounds__(256) void ln_kernel(
    const u16* __restrict__ X, const float* __restrict__ P,
    const u16* __restrict__ g, const u16* __restrict__ bta,
    u16* __restrict__ out, int rows)
{
  const int row = blockIdx.x * 4 + (threadIdx.x >> 6);
  if (row >= rows) return;
  const int lane = threadIdx.x & 63;
  const float* pr = P + (long)row * DM;
  const u16* xr = RES ? (X + (long)row * DM) : nullptr;
  float v[8], s = 0.f, s2 = 0.f;
#pragma unroll
  for (int i = 0; i < 8; ++i) {
    const int jx = i * 64 + lane;
    float t = pr[jx];
    if (RES) t += us2f(xr[jx]);
    v[i] = t; s += t; s2 += t * t;
  }
#pragma unroll
  for (int o = 32; o; o >>= 1) { s += __shfl_xor(s, o); s2 += __shfl_xor(s2, o); }
  const float mean = s * (1.f / DM);
  const float var  = s2 * (1.f / DM) - mean * mean;
  const float rstd = rsqrtf(fmaxf(var, 0.f) + 1e-5f);
  u16* orow = out + (long)row * DM;
#pragma unroll
  for (int i = 0; i < 8; ++i) {
    const int jx = i * 64 + lane;
    orow[jx] = f2us((v[i] - mean) * rstd * us2f(g[jx]) + us2f(bta[jx]));
  }
}

// ---------------------------------------------------------------------------
__global__ __launch_bounds__(256) void evi_gate_kernel(
    const u16* __restrict__ H, const u16* __restrict__ W2, const u16* __restrict__ b2,
    const int* __restrict__ kptr, u16* __restrict__ gout, float* __restrict__ lb, int rows)
{
  const int row = blockIdx.x * 4 + (threadIdx.x >> 6);
  if (row >= rows) return;
  const int lane = threadIdx.x & 63;
  const u16* hr = H + (long)row * DM;
  float p1 = 0.f, p2 = 0.f, p3 = 0.f;
#pragma unroll
  for (int i = 0; i < 8; ++i) {
    const int idx = i * 64 + lane;
    const float hv = us2f(hr[idx]);
    const u16x4 w = *(const u16x4*)&W2[idx * 4];
    p1 += hv * us2f(w[1]);
    p2 += hv * us2f(w[2]); p3 += hv * us2f(w[3]);
  }
#pragma unroll
  for (int o = 32; o; o >>= 1) {
    p1 += __shfl_xor(p1, o);
    p2 += __shfl_xor(p2, o); p3 += __shfl_xor(p3, o);
  }
  if (lane == 0) {
    const float nu = p1 + us2f(b2[1]);
    const float al = p2 + us2f(b2[2]);
    const float be = p3 + us2f(b2[3]);
    auto sp = [](float x) { return x > 20.f ? x : log1pf(expf(x)); };
    const float spn = sp(nu) + 1e-6f;
    const float spa = sp(al);            // alpha - 1
    const float spb = sp(be) + 1e-6f;
    const float sig = spb / (spn * spa);
    const float kk = (float)kptr[0];
    float gg = expf(-kk * sig);
    gg = fminf(fmaxf(gg, 0.05f), 1.f);
    gout[row] = f2us(gg);
    lb[row] = logf(gg + 1e-12f);
  }
}

// ---------------------------------------------------------------------------
extern "C" void kernel_launch(void* const* d_in, const int* in_sizes, int n_in,
                              void* d_out, int out_size, void* d_ws, size_t ws_size,
                              hipStream_t stream)
{
  const int* kptr = (const int*)d_in[2];

  uint8_t* base = (uint8_t*)d_ws;
  size_t off = 0;
  auto take = [&](size_t bytes) -> void* {
    void* p = base + off;
    off += (bytes + 255) & ~(size_t)255;
    return p;
  };
  int* FLAG = (int*)take(256);

  const int sizes[42] = {
    2097152, 8388608,
    262144, 512, 2048, 4,
    262144, 512, 2048, 4,
    262144,262144,262144,262144, 512,512,512,512, 512,512,
    262144,262144,262144,262144, 512,512,512,512, 512,512,
    1048576, 2048, 1048576, 512, 512, 512,
    1048576, 2048, 1048576, 512, 512, 512
  };
  u16* canon[42];
  u16* cbase = (u16*)take(17319944ul * 2 + 256);
  {
    unsigned long coff = 0;
    for (int i = 0; i < 42; ++i) {
      canon[i] = cbase + coff;
      coff += (unsigned long)((sizes[i] + 7) & ~7);
    }
  }
  const u16 *HdC = canon[0], *HpC = canon[1];
  const u16 *evid_w1 = canon[2], *evid_b1 = canon[3], *evid_w2 = canon[4], *evid_b2 = canon[5];
  const u16 *evip_w1 = canon[6], *evip_b1 = canon[7], *evip_w2 = canon[8], *evip_b2 = canon[9];
  const u16 *p2d_wq = canon[10], *p2d_wk = canon[11], *p2d_wv = canon[12], *p2d_wo = canon[13];
  const u16 *p2d_bq = canon[14], *p2d_bk = canon[15], *p2d_bv = canon[16], *p2d_bo = canon[17];
  const u16 *p2d_lng = canon[18], *p2d_lnb = canon[19];
  const u16 *d2p_wq = canon[20], *d2p_wk = canon[21], *d2p_wv = canon[22], *d2p_wo = canon[23];
  const u16 *d2p_bq = canon[24], *d2p_bk = canon[25], *d2p_bv = canon[26], *d2p_bo = canon[27];
  const u16 *d2p_lng = canon[28], *d2p_lnb = canon[29];
  const u16 *ffnd_w1 = canon[30], *ffnd_b1 = canon[31], *ffnd_w2 = canon[32], *ffnd_b2 = canon[33];
  const u16 *ffnd_lng = canon[34], *ffnd_lnb = canon[35];
  const u16 *ffnp_w1 = canon[36], *ffnp_b1 = canon[37], *ffnp_w2 = canon[38], *ffnp_b2 = canon[39];
  const u16 *ffnp_lng = canon[40], *ffnp_lnb = canon[41];

  u16* evid_w1T = (u16*)take(512*512*2);
  u16* evip_w1T = (u16*)take(512*512*2);
  u16* p2d_wqT = (u16*)take(512*512*2);
  u16* p2d_wkT = (u16*)take(512*512*2);
  u16* p2d_wvT = (u16*)take(512*512*2);
  u16* p2d_woT = (u16*)take(512*512*2);
  u16* d2p_wqT = (u16*)take(512*512*2);
  u16* d2p_wkT = (u16*)take(512*512*2);
  u16* d2p_wvT = (u16*)take(512*512*2);
  u16* d2p_woT = (u16*)take(512*512*2);
  u16* ffnd_w1T = (u16*)take(512*2048*2);
  u16* ffnd_w2T = (u16*)take(2048*512*2);
  u16* ffnp_w1T = (u16*)take(512*2048*2);
  u16* ffnp_w2T = (u16*)take(2048*512*2);
  u16*   SBUF = (u16*)take((size_t)16384*2048*2);
  float* PBUF = (float*)take((size_t)16384*512*4);
  u16*   QBUF = (u16*)take((size_t)16384*512*2);
  u16*   KBUF = (u16*)take((size_t)16384*512*2);
  u16*   VTBUF = (u16*)take((size_t)16384*512*2);
  u16*   ABUF = (u16*)take((size_t)16384*512*2);
  u16*   HP2  = (u16*)take((size_t)16384*512*2);
  u16*   HD2  = (u16*)take((size_t)4096*512*2);
  float* LBD  = (float*)take((size_t)NB*TDr*4);
  float* LBP  = (float*)take((size_t)NB*TPr*4);
  u16*   OSTG = (u16*)take((size_t)10506240*2);
  if (off > ws_size) return;

  const long OS_HD = 0;
  const long OS_HP = 2097152;
  const long OS_GD = 10485760;
  const long OS_GP = 10489856;

  detect_kernel<<<dim3(1), 64, 0, stream>>>((const u16*)d_in[0], FLAG);
  CvtTable tbl;
  {
    int ii = 0;
    for (int i = 0; i < 43; ++i) {
      if (i == 2) continue;
      tbl.d[ii].src = d_in[i];
      tbl.d[ii].dst_off = (unsigned long)(canon[ii] - cbase);
      tbl.d[ii].n = sizes[ii];
      ++ii;
    }
  }
  cvt_kernel<<<dim3(64, 42), 256, 0, stream>>>(tbl, cbase, FLAG);

  TTable tt;
  {
    const TTab tts[14] = {
      {evid_w1, evid_w1T, 512, 512}, {evip_w1, evip_w1T, 512, 512},
      {p2d_wq, p2d_wqT, 512, 512}, {p2d_wk, p2d_wkT, 512, 512},
      {p2d_wv, p2d_wvT, 512, 512}, {p2d_wo, p2d_woT, 512, 512},
      {d2p_wq, d2p_wqT, 512, 512}, {d2p_wk, d2p_wkT, 512, 512},
      {d2p_wv, d2p_wvT, 512, 512}, {d2p_wo, d2p_woT, 512, 512},
      {ffnd_w1, ffnd_w1T, 512, 2048}, {ffnd_w2, ffnd_w2T, 2048, 512},
      {ffnp_w1, ffnp_w1T, 512, 2048}, {ffnp_w2, ffnp_w2T, 2048, 512},
    };
    for (int i = 0; i < 14; ++i) tt.d[i] = tts[i];
  }
  transpose_all<<<dim3(16, 16, 14), 256, 0, stream>>>(tt);

  const float SCALE = 0.125f;  // 1/sqrt(64)

  // ---- evidential heads ----
  gemm_nt<128,128,0,1><<<dim3(32,4,1),256,0,stream>>>(
      HdC,0,0,512, evid_w1T,0,0,512, evid_b1, QBUF,0,0,512, nullptr,0,0.f, 512,1,0);
  evi_gate_kernel<<<dim3(4096/4),256,0,stream>>>(QBUF, evid_w2, evid_b2, kptr, OSTG + OS_GD, LBD, 4096);
  gemm_nt<128,128,0,1><<<dim3(128,4,1),256,0,stream>>>(
      HpC,0,0,512, evip_w1T,0,0,512, evip_b1, QBUF,0,0,512, nullptr,0,0.f, 512,1,0);
  evi_gate_kernel<<<dim3(16384/4),256,0,stream>>>(QBUF, evip_w2, evip_b2, kptr, OSTG + OS_GP, LBP, 16384);

  // ---- p2d attention ----
  gemm_nt<128,128,0,0><<<dim3(128,4,1),256,0,stream>>>(
      HpC,0,0,512, p2d_wqT,0,0,512, p2d_bq, QBUF,0,0,512, nullptr,0,0.f, 512,1,0);
  gemm_nt<128,128,0,0><<<dim3(32,4,1),256,0,stream>>>(
      HdC,0,0,512, p2d_wkT,0,0,512, p2d_bk, KBUF,0,0,512, nullptr,0,0.f, 512,1,0);
  gemm_nt<128,128,2,0><<<dim3(32,4,1),256,0,stream>>>(
      HdC,0,0,512, p2d_wvT,0,0,512, p2d_bv, VTBUF,0,0,0, nullptr,0,0.f, 512,1,TDr);
  gemm_nt<128,128,3,0><<<dim3(8,2,128),256,0,stream>>>(
      QBUF,(long)TPr*512,64,512, KBUF,(long)TDr*512,64,512, nullptr,
      SBUF,(long)NH*TPr*TDr,(long)TPr*TDr,TDr, LBD,TDr,SCALE, 64,NH,0);
  softmax_kernel<4><<<dim3(NB*NH*TPr/4),256,0,stream>>>(SBUF);
  gemm_nt<128,64,0,0><<<dim3(8,1,128),256,0,stream>>>(
      SBUF,(long)NH*TPr*TDr,(long)TPr*TDr,TDr, VTBUF,(long)DM*TDr,(long)DHEAD*TDr,TDr, nullptr,
      ABUF,(long)TPr*512,64,512, nullptr,0,0.f, TDr,NH,0);
  gemm_nt<128,128,1,0><<<dim3(128,4,1),256,0,stream>>>(
      ABUF,0,0,512, p2d_woT,0,0,512, p2d_bo, PBUF,0,0,512, nullptr,0,0.f, 512,1,0);
  ln_kernel<1><<<dim3(16384/4),256,0,stream>>>(HpC, PBUF, p2d_lng, p2d_lnb, HP2, 16384);

  // ---- d2p attention ----
  gemm_nt<128,128,0,0><<<dim3(32,4,1),256,0,stream>>>(
      HdC,0,0,512, d2p_wqT,0,0,512, d2p_bq, QBUF,0,0,512, nullptr,0,0.f, 512,1,0);
  gemm_nt<128,128,0,0><<<dim3(128,4,1),256,0,stream>>>(
      HpC,0,0,512, d2p_wkT,0,0,512, d2p_bk, KBUF,0,0,512, nullptr,0,0.f, 512,1,0);
  gemm_nt<128,128,2,0><<<dim3(128,4,1),256,0,stream>>>(
      HpC,0,0,512, d2p_wvT,0,0,512, d2p_bv, VTBUF,0,0,0, nullptr,0,0.f, 512,1,TPr);
  gemm_nt<128,128,3,0><<<dim3(2,8,128),256,0,stream>>>(
      QBUF,(long)TDr*512,64,512, KBUF,(long)TPr*512,64,512, nullptr,
      SBUF,(long)NH*TDr*TPr,(long)TDr*TPr,TPr, LBP,TPr,SCALE, 64,NH,0);
  softmax_kernel<16><<<dim3(NB*NH*TDr/4),256,0,stream>>>(SBUF);
  gemm_nt<128,64,0,0><<<dim3(2,1,128),256,0,stream>>>(
      SBUF,(long)NH*TDr*TPr,(long)TDr*TPr,TPr, VTBUF,(long)DM*TPr,(long)DHEAD*TPr,TPr, nullptr,
      ABUF,(long)TDr*512,64,512, nullptr,0,0.f, TPr,NH,0);
  gemm_nt<128,128,1,0><<<dim3(32,4,1),256,0,stream>>>(
      ABUF,0,0,512, d2p_woT,0,0,512, d2p_bo, PBUF,0,0,512, nullptr,0,0.f, 512,1,0);
  ln_kernel<1><<<dim3(4096/4),256,0,stream>>>(HdC, PBUF, d2p_lng, d2p_lnb, HD2, 4096);

  // ---- FFN p ----
  gemm_nt<128,128,0,1><<<dim3(128,16,1),256,0,stream>>>(
      HP2,0,0,512, ffnp_w1T,0,0,512, ffnp_b1, SBUF,0,0,2048, nullptr,0,0.f, 512,1,0);
  gemm_nt<128,128,1,0><<<dim3(128,4,1),256,0,stream>>>(
      SBUF,0,0,2048, ffnp_w2T,0,0,2048, ffnp_b2, PBUF,0,0,512, nullptr,0,0.f, 2048,1,0);
  ln_kernel<0><<<dim3(16384/4),256,0,stream>>>(nullptr, PBUF, ffnp_lng, ffnp_lnb, OSTG + OS_HP, 16384);

  // ---- FFN d ----
  gemm_nt<128,128,0,1><<<dim3(32,16,1),256,0,stream>>>(
      HD2,0,0,512, ffnd_w1T,0,0,512, ffnd_b1, SBUF,0,0,2048, nullptr,0,0.f, 512,1,0);
  gemm_nt<128,128,1,0><<<dim3(32,4,1),256,0,stream>>>(
      SBUF,0,0,2048, ffnd_w2T,0,0,2048, ffnd_b2, PBUF,0,0,512, nullptr,0,0.f, 2048,1,0);
  ln_kernel<0><<<dim3(4096/4),256,0,stream>>>(nullptr, PBUF, ffnd_lng, ffnd_lnb, OSTG + OS_HD, 4096);

  pack_kernel<<<dim3(1024),256,0,stream>>>(OSTG, d_out, 10506240/8, FLAG);
}

// Round 5
// 568.595 us; speedup vs baseline: 1.1576x; 1.0685x over previous
//
#include <hip/hip_runtime.h>
#include <stdint.h>
#include <math.h>

typedef unsigned short u16;
typedef __attribute__((ext_vector_type(8))) short bf16x8;
typedef __attribute__((ext_vector_type(8))) short short8;
typedef __attribute__((ext_vector_type(4))) float f32x4;
typedef __attribute__((ext_vector_type(4))) unsigned short u16x4;

#define NB 16
#define TDr 256
#define TPr 1024
#define DM 512
#define NH 8
#define DHEAD 64

__device__ __forceinline__ float us2f(u16 u) {
  union { float f; unsigned int i; } x; x.i = ((unsigned int)u) << 16; return x.f;
}
__device__ __forceinline__ u16 f2us(float f) {
  union { float fl; unsigned int i; } x; x.fl = f;
  unsigned int u = x.i;
  return (u16)((u + 0x7fffu + ((u >> 16) & 1u)) >> 16);  // RNE
}

// ---------------------------------------------------------------------------
__global__ __launch_bounds__(64) void detect_kernel(const u16* __restrict__ raw,
                                                    int* __restrict__ flag)
{
  const int lane = threadIdx.x;
  float mx = 0.f;
  for (int i = lane; i < 256; i += 64) {
    float v = us2f(raw[i]);
    v = fabsf(v);
    if (isfinite(v)) mx = fmaxf(mx, v); else mx = 1e30f;
  }
#pragma unroll
  for (int o = 32; o; o >>= 1) mx = fmaxf(mx, __shfl_xor(mx, o));
  if (lane == 0) flag[0] = (mx > 1e10f) ? 1 : 0;
}

// ---------------------------------------------------------------------------
struct CvtDesc { const void* src; unsigned long dst_off; int n; };
struct CvtTable { CvtDesc d[42]; };

__global__ __launch_bounds__(256) void cvt_kernel(CvtTable t, u16* __restrict__ base,
                                                  const int* __restrict__ flag)
{
  const CvtDesc d = t.d[blockIdx.y];
  u16* dst = base + d.dst_off;
  const int isf32 = flag[0];
  const int stride = gridDim.x * 256;
  const int tid0 = blockIdx.x * 256 + threadIdx.x;
  if (d.n >= 8) {
    const int n8 = d.n >> 3;
    if (isf32) {
      const float* s = (const float*)d.src;
      for (int i = tid0; i < n8; i += stride) {
        f32x4 a = *(const f32x4*)&s[i * 8];
        f32x4 b = *(const f32x4*)&s[i * 8 + 4];
        short8 o;
        o[0]=(short)f2us(a[0]); o[1]=(short)f2us(a[1]); o[2]=(short)f2us(a[2]); o[3]=(short)f2us(a[3]);
        o[4]=(short)f2us(b[0]); o[5]=(short)f2us(b[1]); o[6]=(short)f2us(b[2]); o[7]=(short)f2us(b[3]);
        *(short8*)&dst[i * 8] = o;
      }
    } else {
      const short8* s = (const short8*)d.src;
      for (int i = tid0; i < n8; i += stride) *(short8*)&dst[i * 8] = s[i];
    }
  } else {
    if (isf32) {
      const float* s = (const float*)d.src;
      for (int i = tid0; i < d.n; i += stride) dst[i] = f2us(s[i]);
    } else {
      const u16* s = (const u16*)d.src;
      for (int i = tid0; i < d.n; i += stride) dst[i] = s[i];
    }
  }
}

// ---------------------------------------------------------------------------
// NT GEMM, 2-deep global_load_lds pipeline, counted vmcnt (verified round 4)
// EPI: 0 bf16 (+bias, opt SiLU) | 1 f32 (+bias) | 2 bf16 V^T store
// ---------------------------------------------------------------------------
template<int BM, int BN, int EPI, int SILU>
__global__ __launch_bounds__(256) void gemm_nt(
    const u16* __restrict__ A, long sAb, long sAh, int lda,
    const u16* __restrict__ Bt, long sBb, long sBh, int ldb,
    const u16* __restrict__ bias,
    void* __restrict__ Cout, long sCb, long sCh, int ldc,
    float scale, int K, int HH, int ntok)
{
  constexpr int BK = 32;
  constexpr int FM = BM / 32;
  constexpr int FN = BN / 32;
  constexpr int LPT = (BM * BK / 8 + BN * BK / 8) / 256;
  __shared__ __align__(16) u16 As[2][BM * BK];
  __shared__ __align__(16) u16 Bs[2][BN * BK];

  const int tid  = threadIdx.x;
  const int lane = tid & 63;
  const int wm = (tid >> 6) >> 1;
  const int wn = (tid >> 6) & 1;
  const int z  = blockIdx.z;
  const int zb = z / HH;
  const int zh = z - zb * HH;
  const long row0 = (long)blockIdx.x * BM;
  const long col0 = (long)blockIdx.y * BN;

  const u16* Ab = A  + zb * sAb + zh * sAh + row0 * (long)lda;
  const u16* Bb = Bt + zb * sBb + zh * sBh + col0 * (long)ldb;

  f32x4 acc[FM][FN];
#pragma unroll
  for (int i = 0; i < FM; ++i)
#pragma unroll
    for (int j = 0; j < FN; ++j)
      acc[i][j] = (f32x4){0.f, 0.f, 0.f, 0.f};

  auto stage = [&](int buf, int k0) {
#pragma unroll
    for (int c = tid; c < BM * BK / 8; c += 256) {
      const int r  = c >> 2;
      const int kk = (c & 3) << 3;
      __builtin_amdgcn_global_load_lds(
          (const __attribute__((address_space(1))) uint32_t*)(Ab + (long)r * lda + k0 + kk),
          (__attribute__((address_space(3))) uint32_t*)(&As[buf][c * 8]), 16, 0, 0);
    }
#pragma unroll
    for (int c = tid; c < BN * BK / 8; c += 256) {
      const int r  = c >> 2;
      const int kk = (c & 3) << 3;
      __builtin_amdgcn_global_load_lds(
          (const __attribute__((address_space(1))) uint32_t*)(Bb + (long)r * ldb + k0 + kk),
          (__attribute__((address_space(3))) uint32_t*)(&Bs[buf][c * 8]), 16, 0, 0);
    }
  };

  const int nt = K / BK;
  stage(0, 0);
  if (nt > 1) stage(1, BK);

  for (int t = 0; t < nt; ++t) {
    if (t + 1 < nt) {
      if constexpr (LPT == 4) asm volatile("s_waitcnt vmcnt(4)" ::: "memory");
      else                    asm volatile("s_waitcnt vmcnt(3)" ::: "memory");
    } else {
      asm volatile("s_waitcnt vmcnt(0)" ::: "memory");
    }
    asm volatile("s_barrier" ::: "memory");
    __builtin_amdgcn_sched_barrier(0);

    const int cur = t & 1;
    bf16x8 af[FM], bfv[FN];
#pragma unroll
    for (int i = 0; i < FM; ++i)
      af[i] = *(const bf16x8*)&As[cur][(wm * (BM/2) + i*16 + (lane & 15)) * BK + ((lane >> 4) << 3)];
#pragma unroll
    for (int j = 0; j < FN; ++j)
      bfv[j] = *(const bf16x8*)&Bs[cur][(wn * (BN/2) + j*16 + (lane & 15)) * BK + ((lane >> 4) << 3)];
#pragma unroll
    for (int i = 0; i < FM; ++i)
#pragma unroll
      for (int j = 0; j < FN; ++j)
        acc[i][j] = __builtin_amdgcn_mfma_f32_16x16x32_bf16(af[i], bfv[j], acc[i][j], 0, 0, 0);

    __builtin_amdgcn_sched_barrier(0);
    asm volatile("s_barrier" ::: "memory");
    __builtin_amdgcn_sched_barrier(0);
    if (t + 2 < nt) stage(cur, (t + 2) * BK);
  }

#pragma unroll
  for (int i = 0; i < FM; ++i) {
    const long gr0 = row0 + wm * (BM/2) + i * 16 + ((lane >> 4) << 2);
#pragma unroll
    for (int j = 0; j < FN; ++j) {
      const long gc = col0 + wn * (BN/2) + j * 16 + (lane & 15);
      const float badd = bias ? us2f(bias[gc]) : 0.f;
      if constexpr (EPI == 2) {
        const long bb = gr0 / ntok;
        const long t0 = gr0 - bb * ntok;
        u16* dst = (u16*)Cout + bb * ((long)DM * ntok) + gc * (long)ntok + t0;
        u16x4 pk;
#pragma unroll
        for (int r = 0; r < 4; ++r) pk[r] = f2us(acc[i][j][r] + badd);
        *(u16x4*)dst = pk;
      } else if constexpr (EPI == 1) {
        float* Cf = (float*)Cout + zb * sCb + zh * sCh;
#pragma unroll
        for (int r = 0; r < 4; ++r) {
          float v = acc[i][j][r] + badd;
          if (SILU) v = v / (1.f + __expf(-v));
          Cf[(gr0 + r) * (long)ldc + gc] = v;
        }
      } else {
        u16* Cb = (u16*)Cout + zb * sCb + zh * sCh;
#pragma unroll
        for (int r = 0; r < 4; ++r) {
          float v = acc[i][j][r] + badd;
          if (SILU) v = v / (1.f + __expf(-v));
          Cb[(gr0 + r) * (long)ldc + gc] = f2us(v);
        }
      }
    }
  }
}

// ---------------------------------------------------------------------------
// Fused attention: S = Q·K^T*scale + lb; softmax; O = P·V.
// Block = one (b,h) + 128 q-rows; 4 independent waves (32 rows each), no
// cross-wave sync. Q/K/V frags direct from global; P via padded LDS.
// ---------------------------------------------------------------------------
template<int NKV>
__global__ __launch_bounds__(256) void attn_fused(
    const u16* __restrict__ Qp, const u16* __restrict__ Kp,
    const u16* __restrict__ Vt, const float* __restrict__ lb,
    u16* __restrict__ Aout, int M)
{
  constexpr int CH = 128;
  constexpr int NC = NKV / CH;
  constexpr int PLD = 136;
  __shared__ __align__(16) u16 Ps[4][32][PLD];

  const int tid  = threadIdx.x;
  const int lane = tid & 63;
  const int w    = tid >> 6;
  const int bh = blockIdx.y;
  const int b = bh >> 3, h = bh & 7;
  const long q0 = (long)blockIdx.x * 128;

  const u16* Qb = Qp + ((long)b * M + q0) * DM + h * DHEAD;
  const u16* Kb = Kp + (long)b * NKV * DM + h * DHEAD;
  const u16* Vb = Vt + ((long)b * DM + h * DHEAD) * NKV;
  const float* lbb = lb + (long)b * NKV;

  const int r16 = lane & 15;
  const int k8  = (lane >> 4) << 3;
  const int rr4 = (lane >> 4) << 2;
  const float SCALE = 0.125f;

  bf16x8 qa[2][2];
#pragma unroll
  for (int i = 0; i < 2; ++i)
#pragma unroll
    for (int kc = 0; kc < 2; ++kc)
      qa[i][kc] = *(const bf16x8*)&Qb[(long)(w*32 + i*16 + r16) * DM + kc*32 + k8];

  f32x4 acc_o[2][4];
#pragma unroll
  for (int i = 0; i < 2; ++i)
#pragma unroll
    for (int jo = 0; jo < 4; ++jo)
      acc_o[i][jo] = (f32x4){0.f, 0.f, 0.f, 0.f};
  float mrow[8], lrow[8];
#pragma unroll
  for (int s = 0; s < 8; ++s) { mrow[s] = -1e30f; lrow[s] = 0.f; }

  for (int c = 0; c < NC; ++c) {
    const int t0 = c * CH;
    f32x4 acc_s[2][8];
#pragma unroll
    for (int i = 0; i < 2; ++i)
#pragma unroll
      for (int j = 0; j < 8; ++j)
        acc_s[i][j] = (f32x4){0.f, 0.f, 0.f, 0.f};
#pragma unroll
    for (int j = 0; j < 8; ++j) {
      const long trow = t0 + j*16 + r16;
      bf16x8 kb0 = *(const bf16x8*)&Kb[trow * DM + k8];
      bf16x8 kb1 = *(const bf16x8*)&Kb[trow * DM + 32 + k8];
#pragma unroll
      for (int i = 0; i < 2; ++i) {
        acc_s[i][j] = __builtin_amdgcn_mfma_f32_16x16x32_bf16(qa[i][0], kb0, acc_s[i][j], 0, 0, 0);
        acc_s[i][j] = __builtin_amdgcn_mfma_f32_16x16x32_bf16(qa[i][1], kb1, acc_s[i][j], 0, 0, 0);
      }
    }

    float lbv[8];
#pragma unroll
    for (int j = 0; j < 8; ++j) lbv[j] = lbb[t0 + j*16 + r16];
    float pm[8];
#pragma unroll
    for (int s = 0; s < 8; ++s) pm[s] = -1e30f;
#pragma unroll
    for (int i = 0; i < 2; ++i)
#pragma unroll
      for (int j = 0; j < 8; ++j)
#pragma unroll
        for (int r = 0; r < 4; ++r) {
          float v = acc_s[i][j][r] * SCALE + lbv[j];
          acc_s[i][j][r] = v;
          pm[i*4 + r] = fmaxf(pm[i*4 + r], v);
        }
#pragma unroll
    for (int s = 0; s < 8; ++s) {
#pragma unroll
      for (int o = 1; o < 16; o <<= 1) pm[s] = fmaxf(pm[s], __shfl_xor(pm[s], o));
    }
    float sc[8];
#pragma unroll
    for (int s = 0; s < 8; ++s) {
      const float mn = fmaxf(mrow[s], pm[s]);
      sc[s] = __expf(mrow[s] - mn);
      mrow[s] = mn;
      lrow[s] *= sc[s];
    }
#pragma unroll
    for (int i = 0; i < 2; ++i)
#pragma unroll
      for (int jo = 0; jo < 4; ++jo)
#pragma unroll
        for (int r = 0; r < 4; ++r)
          acc_o[i][jo][r] *= sc[i*4 + r];

    float ls[8];
#pragma unroll
    for (int s = 0; s < 8; ++s) ls[s] = 0.f;
#pragma unroll
    for (int i = 0; i < 2; ++i)
#pragma unroll
      for (int j = 0; j < 8; ++j)
#pragma unroll
        for (int r = 0; r < 4; ++r) {
          const float p = __expf(acc_s[i][j][r] - mrow[i*4 + r]);
          ls[i*4 + r] += p;
          Ps[w][i*16 + rr4 + r][j*16 + r16] = f2us(p);
        }
#pragma unroll
    for (int s = 0; s < 8; ++s) {
#pragma unroll
      for (int o = 1; o < 16; o <<= 1) ls[s] += __shfl_xor(ls[s], o);
      lrow[s] += ls[s];
    }

    asm volatile("s_waitcnt lgkmcnt(0)" ::: "memory");
    __builtin_amdgcn_sched_barrier(0);

#pragma unroll
    for (int kc = 0; kc < 4; ++kc) {
      bf16x8 pa[2];
#pragma unroll
      for (int i = 0; i < 2; ++i)
        pa[i] = *(const bf16x8*)&Ps[w][i*16 + r16][kc*32 + k8];
#pragma unroll
      for (int jo = 0; jo < 4; ++jo) {
        bf16x8 vb = *(const bf16x8*)&Vb[(long)(jo*16 + r16) * NKV + t0 + kc*32 + k8];
#pragma unroll
        for (int i = 0; i < 2; ++i)
          acc_o[i][jo] = __builtin_amdgcn_mfma_f32_16x16x32_bf16(pa[i], vb, acc_o[i][jo], 0, 0, 0);
      }
    }
    __builtin_amdgcn_sched_barrier(0);
  }

  float linv[8];
#pragma unroll
  for (int s = 0; s < 8; ++s) linv[s] = 1.f / lrow[s];
  u16* Ob = Aout + ((long)b * M + q0) * DM + h * DHEAD;
#pragma unroll
  for (int i = 0; i < 2; ++i)
#pragma unroll
    for (int jo = 0; jo < 4; ++jo)
#pragma unroll
      for (int r = 0; r < 4; ++r) {
        const long row = w*32 + i*16 + rr4 + r;
        Ob[row * DM + jo*16 + r16] = f2us(acc_o[i][jo][r] * linv[i*4 + r]);
      }
}

// ---------------------------------------------------------------------------
struct TTab { const u16* in; u16* out; int R, C; };
struct TTable { TTab d[14]; };

__global__ __launch_bounds__(256) void transpose_all(TTable tt)
{
  const TTab d = tt.d[blockIdx.z];
  __shared__ u16 t[32][33];
  const int tx = threadIdx.x & 31, ty = threadIdx.x >> 5;
  for (int r0 = blockIdx.y * 32; r0 < d.R; r0 += gridDim.y * 32) {
    for (int c0 = blockIdx.x * 32; c0 < d.C; c0 += gridDim.x * 32) {
#pragma unroll
      for (int i = 0; i < 4; ++i)
        t[ty + 8*i][tx] = d.in[(long)(r0 + ty + 8*i) * d.C + c0 + tx];
      __syncthreads();
#pragma unroll
      for (int i = 0; i < 4; ++i)
        d.out[(long)(c0 + ty + 8*i) * d.R + r0 + tx] = t[tx][ty + 8*i];
      __syncthreads();
    }
  }
}

// ---------------------------------------------------------------------------
template<int RES, int DIRECT>
__global__ __launch_bounds__(256) void ln_kernel(
    const u16* __restrict__ X, const float* __restrict__ P,
    const u16* __restrict__ g, const u16* __restrict__ bta,
    void* __restrict__ outbase, long oofs, int rows, const int* __restrict__ flag)
{
  const int row = blockIdx.x * 4 + (threadIdx.x >> 6);
  if (row >= rows) return;
  const int lane = threadIdx.x & 63;
  const float* pr = P + (long)row * DM;
  const u16* xr = RES ? (X + (long)row * DM) : nullptr;
  float v[8], s = 0.f, s2 = 0.f;
#pragma unroll
  for (int i = 0; i < 8; ++i) {
    const int jx = i * 64 + lane;
    float t = pr[jx];
    if (RES) t += us2f(xr[jx]);
    v[i] = t; s += t; s2 += t * t;
  }
#pragma unroll
  for (int o = 32; o; o >>= 1) { s += __shfl_xor(s, o); s2 += __shfl_xor(s2, o); }
  const float mean = s * (1.f / DM);
  const float var  = s2 * (1.f / DM) - mean * mean;
  const float rstd = rsqrtf(fmaxf(var, 0.f) + 1e-5f);
  const int isf32 = DIRECT ? flag[0] : 0;
#pragma unroll
  for (int i = 0; i < 8; ++i) {
    const int jx = i * 64 + lane;
    const float ov = (v[i] - mean) * rstd * us2f(g[jx]) + us2f(bta[jx]);
    if (DIRECT && isf32) ((float*)outbase)[oofs + (long)row * DM + jx] = ov;
    else                 ((u16*)outbase)[oofs + (long)row * DM + jx] = f2us(ov);
  }
}

// ---------------------------------------------------------------------------
__global__ __launch_bounds__(256) void evi_gate_kernel(
    const u16* __restrict__ H, const u16* __restrict__ W2, const u16* __restrict__ b2,
    const int* __restrict__ kptr, void* __restrict__ outbase, long oofs,
    float* __restrict__ lbo, int rows, const int* __restrict__ flag)
{
  const int row = blockIdx.x * 4 + (threadIdx.x >> 6);
  if (row >= rows) return;
  const int lane = threadIdx.x & 63;
  const u16* hr = H + (long)row * DM;
  float p1 = 0.f, p2 = 0.f, p3 = 0.f;
#pragma unroll
  for (int i = 0; i < 8; ++i) {
    const int idx = i * 64 + lane;
    const float hv = us2f(hr[idx]);
    const u16x4 w = *(const u16x4*)&W2[idx * 4];
    p1 += hv * us2f(w[1]);
    p2 += hv * us2f(w[2]); p3 += hv * us2f(w[3]);
  }
#pragma unroll
  for (int o = 32; o; o >>= 1) {
    p1 += __shfl_xor(p1, o);
    p2 += __shfl_xor(p2, o); p3 += __shfl_xor(p3, o);
  }
  if (lane == 0) {
    const float nu = p1 + us2f(b2[1]);
    const float al = p2 + us2f(b2[2]);
    const float be = p3 + us2f(b2[3]);
    auto sp = [](float x) { return x > 20.f ? x : log1pf(expf(x)); };
    const float spn = sp(nu) + 1e-6f;
    const float spa = sp(al);
    const float spb = sp(be) + 1e-6f;
    const float sig = spb / (spn * spa);
    const float kk = (float)kptr[0];
    float gg = expf(-kk * sig);
    gg = fminf(fmaxf(gg, 0.05f), 1.f);
    if (flag[0]) ((float*)outbase)[oofs + row] = gg;
    else         ((u16*)outbase)[oofs + row] = f2us(gg);
    lbo[row] = logf(gg + 1e-12f);
  }
}

// ---------------------------------------------------------------------------
extern "C" void kernel_launch(void* const* d_in, const int* in_sizes, int n_in,
                              void* d_out, int out_size, void* d_ws, size_t ws_size,
                              hipStream_t stream)
{
  const int* kptr = (const int*)d_in[2];

  uint8_t* base = (uint8_t*)d_ws;
  size_t off = 0;
  auto take = [&](size_t bytes) -> void* {
    void* p = base + off;
    off += (bytes + 255) & ~(size_t)255;
    return p;
  };
  int* FLAG = (int*)take(256);

  const int sizes[42] = {
    2097152, 8388608,
    262144, 512, 2048, 4,
    262144, 512, 2048, 4,
    262144,262144,262144,262144, 512,512,512,512, 512,512,
    262144,262144,262144,262144, 512,512,512,512, 512,512,
    1048576, 2048, 1048576, 512, 512, 512,
    1048576, 2048, 1048576, 512, 512, 512
  };
  u16* canon[42];
  u16* cbase = (u16*)take(17319944ul * 2 + 256);
  {
    unsigned long coff = 0;
    for (int i = 0; i < 42; ++i) {
      canon[i] = cbase + coff;
      coff += (unsigned long)((sizes[i] + 7) & ~7);
    }
  }
  const u16 *HdC = canon[0], *HpC = canon[1];
  const u16 *evid_w1 = canon[2], *evid_b1 = canon[3], *evid_w2 = canon[4], *evid_b2 = canon[5];
  const u16 *evip_w1 = canon[6], *evip_b1 = canon[7], *evip_w2 = canon[8], *evip_b2 = canon[9];
  const u16 *p2d_wq = canon[10], *p2d_wk = canon[11], *p2d_wv = canon[12], *p2d_wo = canon[13];
  const u16 *p2d_bq = canon[14], *p2d_bk = canon[15], *p2d_bv = canon[16], *p2d_bo = canon[17];
  const u16 *p2d_lng = canon[18], *p2d_lnb = canon[19];
  const u16 *d2p_wq = canon[20], *d2p_wk = canon[21], *d2p_wv = canon[22], *d2p_wo = canon[23];
  const u16 *d2p_bq = canon[24], *d2p_bk = canon[25], *d2p_bv = canon[26], *d2p_bo = canon[27];
  const u16 *d2p_lng = canon[28], *d2p_lnb = canon[29];
  const u16 *ffnd_w1 = canon[30], *ffnd_b1 = canon[31], *ffnd_w2 = canon[32], *ffnd_b2 = canon[33];
  const u16 *ffnd_lng = canon[34], *ffnd_lnb = canon[35];
  const u16 *ffnp_w1 = canon[36], *ffnp_b1 = canon[37], *ffnp_w2 = canon[38], *ffnp_b2 = canon[39];
  const u16 *ffnp_lng = canon[40], *ffnp_lnb = canon[41];

  u16* evid_w1T = (u16*)take(512*512*2);
  u16* evip_w1T = (u16*)take(512*512*2);
  u16* p2d_wqT = (u16*)take(512*512*2);
  u16* p2d_wkT = (u16*)take(512*512*2);
  u16* p2d_wvT = (u16*)take(512*512*2);
  u16* p2d_woT = (u16*)take(512*512*2);
  u16* d2p_wqT = (u16*)take(512*512*2);
  u16* d2p_wkT = (u16*)take(512*512*2);
  u16* d2p_wvT = (u16*)take(512*512*2);
  u16* d2p_woT = (u16*)take(512*512*2);
  u16* ffnd_w1T = (u16*)take(512*2048*2);
  u16* ffnd_w2T = (u16*)take(2048*512*2);
  u16* ffnp_w1T = (u16*)take(512*2048*2);
  u16* ffnp_w2T = (u16*)take(2048*512*2);
  u16*   SBUF = (u16*)take((size_t)16384*2048*2);
  float* PBUF = (float*)take((size_t)16384*512*4);
  u16*   QBUF = (u16*)take((size_t)16384*512*2);
  u16*   KBUF = (u16*)take((size_t)16384*512*2);
  u16*   VTBUF = (u16*)take((size_t)16384*512*2);
  u16*   ABUF = (u16*)take((size_t)16384*512*2);
  u16*   HP2  = (u16*)take((size_t)16384*512*2);
  u16*   HD2  = (u16*)take((size_t)4096*512*2);
  float* LBD  = (float*)take((size_t)NB*TDr*4);
  float* LBP  = (float*)take((size_t)NB*TPr*4);
  if (off > ws_size) return;

  const long O_HD = 0;
  const long O_HP = 2097152;
  const long O_GD = 10485760;
  const long O_GP = 10489856;

  detect_kernel<<<dim3(1), 64, 0, stream>>>((const u16*)d_in[0], FLAG);
  CvtTable tbl;
  {
    int ii = 0;
    for (int i = 0; i < 43; ++i) {
      if (i == 2) continue;
      tbl.d[ii].src = d_in[i];
      tbl.d[ii].dst_off = (unsigned long)(canon[ii] - cbase);
      tbl.d[ii].n = sizes[ii];
      ++ii;
    }
  }
  cvt_kernel<<<dim3(64, 42), 256, 0, stream>>>(tbl, cbase, FLAG);

  TTable tt;
  {
    const TTab tts[14] = {
      {evid_w1, evid_w1T, 512, 512}, {evip_w1, evip_w1T, 512, 512},
      {p2d_wq, p2d_wqT, 512, 512}, {p2d_wk, p2d_wkT, 512, 512},
      {p2d_wv, p2d_wvT, 512, 512}, {p2d_wo, p2d_woT, 512, 512},
      {d2p_wq, d2p_wqT, 512, 512}, {d2p_wk, d2p_wkT, 512, 512},
      {d2p_wv, d2p_wvT, 512, 512}, {d2p_wo, d2p_woT, 512, 512},
      {ffnd_w1, ffnd_w1T, 512, 2048}, {ffnd_w2, ffnd_w2T, 2048, 512},
      {ffnp_w1, ffnp_w1T, 512, 2048}, {ffnp_w2, ffnp_w2T, 2048, 512},
    };
    for (int i = 0; i < 14; ++i) tt.d[i] = tts[i];
  }
  transpose_all<<<dim3(16, 16, 14), 256, 0, stream>>>(tt);

  // ---- evidential heads ----
  gemm_nt<128,128,0,1><<<dim3(32,4,1),256,0,stream>>>(
      HdC,0,0,512, evid_w1T,0,0,512, evid_b1, QBUF,0,0,512, 0.f, 512,1,0);
  evi_gate_kernel<<<dim3(4096/4),256,0,stream>>>(QBUF, evid_w2, evid_b2, kptr,
      d_out, O_GD, LBD, 4096, FLAG);
  gemm_nt<128,128,0,1><<<dim3(128,4,1),256,0,stream>>>(
      HpC,0,0,512, evip_w1T,0,0,512, evip_b1, QBUF,0,0,512, 0.f, 512,1,0);
  evi_gate_kernel<<<dim3(16384/4),256,0,stream>>>(QBUF, evip_w2, evip_b2, kptr,
      d_out, O_GP, LBP, 16384, FLAG);

  // ---- p2d attention: Q=Hp, KV=Hd, bias=log(gd) ----
  gemm_nt<128,128,0,0><<<dim3(128,4,1),256,0,stream>>>(
      HpC,0,0,512, p2d_wqT,0,0,512, p2d_bq, QBUF,0,0,512, 0.f, 512,1,0);
  gemm_nt<128,128,0,0><<<dim3(32,4,1),256,0,stream>>>(
      HdC,0,0,512, p2d_wkT,0,0,512, p2d_bk, KBUF,0,0,512, 0.f, 512,1,0);
  gemm_nt<128,128,2,0><<<dim3(32,4,1),256,0,stream>>>(
      HdC,0,0,512, p2d_wvT,0,0,512, p2d_bv, VTBUF,0,0,0, 0.f, 512,1,TDr);
  attn_fused<TDr><<<dim3(TPr/128, NB*NH), 256, 0, stream>>>(
      QBUF, KBUF, VTBUF, LBD, ABUF, TPr);
  gemm_nt<128,128,1,0><<<dim3(128,4,1),256,0,stream>>>(
      ABUF,0,0,512, p2d_woT,0,0,512, p2d_bo, PBUF,0,0,512, 0.f, 512,1,0);
  ln_kernel<1,0><<<dim3(16384/4),256,0,stream>>>(HpC, PBUF, p2d_lng, p2d_lnb, HP2, 0, 16384, FLAG);

  // ---- d2p attention: Q=Hd, KV=Hp, bias=log(gp) ----
  gemm_nt<128,128,0,0><<<dim3(32,4,1),256,0,stream>>>(
      HdC,0,0,512, d2p_wqT,0,0,512, d2p_bq, QBUF,0,0,512, 0.f, 512,1,0);
  gemm_nt<128,128,0,0><<<dim3(128,4,1),256,0,stream>>>(
      HpC,0,0,512, d2p_wkT,0,0,512, d2p_bk, KBUF,0,0,512, 0.f, 512,1,0);
  gemm_nt<128,128,2,0><<<dim3(128,4,1),256,0,stream>>>(
      HpC,0,0,512, d2p_wvT,0,0,512, d2p_bv, VTBUF,0,0,0, 0.f, 512,1,TPr);
  attn_fused<TPr><<<dim3(TDr/128, NB*NH), 256, 0, stream>>>(
      QBUF, KBUF, VTBUF, LBP, ABUF, TDr);
  gemm_nt<128,128,1,0><<<dim3(32,4,1),256,0,stream>>>(
      ABUF,0,0,512, d2p_woT,0,0,512, d2p_bo, PBUF,0,0,512, 0.f, 512,1,0);
  ln_kernel<1,0><<<dim3(4096/4),256,0,stream>>>(HdC, PBUF, d2p_lng, d2p_lnb, HD2, 0, 4096, FLAG);

  // ---- FFN p ----
  gemm_nt<128,128,0,1><<<dim3(128,16,1),256,0,stream>>>(
      HP2,0,0,512, ffnp_w1T,0,0,512, ffnp_b1, SBUF,0,0,2048, 0.f, 512,1,0);
  gemm_nt<128,128,1,0><<<dim3(128,4,1),256,0,stream>>>(
      SBUF,0,0,2048, ffnp_w2T,0,0,2048, ffnp_b2, PBUF,0,0,512, 0.f, 2048,1,0);
  ln_kernel<0,1><<<dim3(16384/4),256,0,stream>>>(nullptr, PBUF, ffnp_lng, ffnp_lnb,
      d_out, O_HP, 16384, FLAG);

  // ---- FFN d ----
  gemm_nt<128,128,0,1><<<dim3(32,16,1),256,0,stream>>>(
      HD2,0,0,512, ffnd_w1T,0,0,512, ffnd_b1, SBUF,0,0,2048, 0.f, 512,1,0);
  gemm_nt<128,128,1,0><<<dim3(32,4,1),256,0,stream>>>(
      SBUF,0,0,2048, ffnd_w2T,0,0,2048, ffnd_b2, PBUF,0,0,512, 0.f, 2048,1,0);
  ln_kernel<0,1><<<dim3(4096/4),256,0,stream>>>(nullptr, PBUF, ffnd_lng, ffnd_lnb,
      d_out, O_HD, 4096, FLAG);
}

// Round 6
// 485.887 us; speedup vs baseline: 1.3547x; 1.1702x over previous
//
#include <hip/hip_runtime.h>
#include <stdint.h>
#include <math.h>

typedef unsigned short u16;
typedef __attribute__((ext_vector_type(8))) short bf16x8;
typedef __attribute__((ext_vector_type(8))) short short8;
typedef __attribute__((ext_vector_type(4))) float f32x4;
typedef __attribute__((ext_vector_type(4))) unsigned short u16x4;

#define NB 16
#define TDr 256
#define TPr 1024
#define DM 512
#define NH 8
#define DHEAD 64

__device__ __forceinline__ float us2f(u16 u) {
  union { float f; unsigned int i; } x; x.i = ((unsigned int)u) << 16; return x.f;
}
__device__ __forceinline__ u16 f2us(float f) {
  union { float fl; unsigned int i; } x; x.fl = f;
  unsigned int u = x.i;
  return (u16)((u + 0x7fffu + ((u >> 16) & 1u)) >> 16);  // RNE
}

// ---------------------------------------------------------------------------
__global__ __launch_bounds__(64) void detect_kernel(const u16* __restrict__ raw,
                                                    int* __restrict__ flag)
{
  const int lane = threadIdx.x;
  float mx = 0.f;
  for (int i = lane; i < 256; i += 64) {
    float v = us2f(raw[i]);
    v = fabsf(v);
    if (isfinite(v)) mx = fmaxf(mx, v); else mx = 1e30f;
  }
#pragma unroll
  for (int o = 32; o; o >>= 1) mx = fmaxf(mx, __shfl_xor(mx, o));
  if (lane == 0) flag[0] = (mx > 1e10f) ? 1 : 0;
}

// ---------------------------------------------------------------------------
struct CvtDesc { const void* src; unsigned long dst_off; int n; };
struct CvtTable { CvtDesc d[42]; };

__global__ __launch_bounds__(256) void cvt_kernel(CvtTable t, u16* __restrict__ base,
                                                  const int* __restrict__ flag)
{
  const CvtDesc d = t.d[blockIdx.y];
  u16* dst = base + d.dst_off;
  const int isf32 = flag[0];
  const int stride = gridDim.x * 256;
  const int tid0 = blockIdx.x * 256 + threadIdx.x;
  if (d.n >= 8) {
    const int n8 = d.n >> 3;
    if (isf32) {
      const float* s = (const float*)d.src;
      for (int i = tid0; i < n8; i += stride) {
        f32x4 a = *(const f32x4*)&s[i * 8];
        f32x4 b = *(const f32x4*)&s[i * 8 + 4];
        short8 o;
        o[0]=(short)f2us(a[0]); o[1]=(short)f2us(a[1]); o[2]=(short)f2us(a[2]); o[3]=(short)f2us(a[3]);
        o[4]=(short)f2us(b[0]); o[5]=(short)f2us(b[1]); o[6]=(short)f2us(b[2]); o[7]=(short)f2us(b[3]);
        *(short8*)&dst[i * 8] = o;
      }
    } else {
      const short8* s = (const short8*)d.src;
      for (int i = tid0; i < n8; i += stride) *(short8*)&dst[i * 8] = s[i];
    }
  } else {
    if (isf32) {
      const float* s = (const float*)d.src;
      for (int i = tid0; i < d.n; i += stride) dst[i] = f2us(s[i]);
    } else {
      const u16* s = (const u16*)d.src;
      for (int i = tid0; i < d.n; i += stride) dst[i] = s[i];
    }
  }
}

// ---------------------------------------------------------------------------
// Shared GEMM core: 128x128 tile, BK=32, 2-deep global_load_lds pipeline with
// counted vmcnt (verified +13% round 4). lda = ldb = K.
// ---------------------------------------------------------------------------
template<int BM, int BN>
__device__ __forceinline__ void gemm_core(
    const u16* __restrict__ Ab, const u16* __restrict__ Bb,
    int K, int tid, f32x4 (&acc)[BM/32][BN/32])
{
  constexpr int BK = 32;
  constexpr int FM = BM / 32;
  constexpr int FN = BN / 32;
  constexpr int LPT = (BM * BK / 8 + BN * BK / 8) / 256;
  __shared__ __align__(16) u16 As[2][BM * BK];
  __shared__ __align__(16) u16 Bs[2][BN * BK];

  const int lane = tid & 63;
  const int wm = (tid >> 6) >> 1;
  const int wn = (tid >> 6) & 1;

#pragma unroll
  for (int i = 0; i < FM; ++i)
#pragma unroll
    for (int j = 0; j < FN; ++j)
      acc[i][j] = (f32x4){0.f, 0.f, 0.f, 0.f};

  auto stage = [&](int buf, int k0) {
#pragma unroll
    for (int c = tid; c < BM * BK / 8; c += 256) {
      const int r  = c >> 2;
      const int kk = (c & 3) << 3;
      __builtin_amdgcn_global_load_lds(
          (const __attribute__((address_space(1))) uint32_t*)(Ab + (long)r * K + k0 + kk),
          (__attribute__((address_space(3))) uint32_t*)(&As[buf][c * 8]), 16, 0, 0);
    }
#pragma unroll
    for (int c = tid; c < BN * BK / 8; c += 256) {
      const int r  = c >> 2;
      const int kk = (c & 3) << 3;
      __builtin_amdgcn_global_load_lds(
          (const __attribute__((address_space(1))) uint32_t*)(Bb + (long)r * K + k0 + kk),
          (__attribute__((address_space(3))) uint32_t*)(&Bs[buf][c * 8]), 16, 0, 0);
    }
  };

  const int nt = K / BK;
  stage(0, 0);
  if (nt > 1) stage(1, BK);

  for (int t = 0; t < nt; ++t) {
    if (t + 1 < nt) {
      if constexpr (LPT == 4) asm volatile("s_waitcnt vmcnt(4)" ::: "memory");
      else                    asm volatile("s_waitcnt vmcnt(3)" ::: "memory");
    } else {
      asm volatile("s_waitcnt vmcnt(0)" ::: "memory");
    }
    asm volatile("s_barrier" ::: "memory");
    __builtin_amdgcn_sched_barrier(0);

    const int cur = t & 1;
    bf16x8 af[FM], bfv[FN];
#pragma unroll
    for (int i = 0; i < FM; ++i)
      af[i] = *(const bf16x8*)&As[cur][(wm * (BM/2) + i*16 + (lane & 15)) * BK + ((lane >> 4) << 3)];
#pragma unroll
    for (int j = 0; j < FN; ++j)
      bfv[j] = *(const bf16x8*)&Bs[cur][(wn * (BN/2) + j*16 + (lane & 15)) * BK + ((lane >> 4) << 3)];
#pragma unroll
    for (int i = 0; i < FM; ++i)
#pragma unroll
      for (int j = 0; j < FN; ++j)
        acc[i][j] = __builtin_amdgcn_mfma_f32_16x16x32_bf16(af[i], bfv[j], acc[i][j], 0, 0, 0);

    __builtin_amdgcn_sched_barrier(0);
    asm volatile("s_barrier" ::: "memory");
    __builtin_amdgcn_sched_barrier(0);
    if (t + 2 < nt) stage(cur, (t + 2) * BK);
  }
}

// ---------------------------------------------------------------------------
// Fused projection pair: C = A(M,512) @ Wcat(2048,512)^T, epilogue routes
// 512-col ranges: [0:512) evi-h (SiLU), [512:1024) Q, [1024:1536) K,
// [1536:2048) V stored head-transposed VT[b][dcol][t].
// z picks the {Hp,Hd} set; blocks past mtiles return.
// ---------------------------------------------------------------------------
struct ProjSet {
  const u16 *A, *W, *bE, *bQ, *bK, *bV;
  u16 *H, *Q, *Kc, *VT;
  int ntokLog, mtiles;
};

__global__ __launch_bounds__(256) void proj_pair(ProjSet s0, ProjSet s1)
{
  const ProjSet S = blockIdx.z ? s1 : s0;
  if ((int)blockIdx.x >= S.mtiles) return;
  const int tid = threadIdx.x;
  const int lane = tid & 63;
  const int wm = (tid >> 6) >> 1, wn = (tid >> 6) & 1;
  const int r16 = lane & 15, rr4 = (lane >> 4) << 2;
  const long row0 = (long)blockIdx.x * 128;
  const long col0 = (long)blockIdx.y * 128;

  f32x4 acc[4][4];
  gemm_core<128,128>(S.A + row0 * 512, S.W + col0 * 512, 512, tid, acc);

  const int range = (int)(col0 >> 9);
  const u16* bp = range == 0 ? S.bE : range == 1 ? S.bQ : range == 2 ? S.bK : S.bV;
  u16* dst = range == 0 ? S.H : range == 1 ? S.Q : S.Kc;
  const int ntok = 1 << S.ntokLog;

#pragma unroll
  for (int i = 0; i < 4; ++i) {
    const long gr0 = row0 + wm*64 + i*16 + rr4;
#pragma unroll
    for (int j = 0; j < 4; ++j) {
      const int cr = (int)(col0 & 511) + wn*64 + j*16 + r16;
      const float badd = us2f(bp[cr]);
      if (range == 3) {
        const long b = gr0 >> S.ntokLog;
        const long t0 = gr0 & (ntok - 1);
        u16x4 pk;
#pragma unroll
        for (int r = 0; r < 4; ++r) pk[r] = f2us(acc[i][j][r] + badd);
        *(u16x4*)&S.VT[((long)b * 512 + cr) * ntok + t0] = pk;
      } else if (range == 0) {
#pragma unroll
        for (int r = 0; r < 4; ++r) {
          float v = acc[i][j][r] + badd;
          v = v / (1.f + __expf(-v));
          dst[(gr0 + r) * 512 + cr] = f2us(v);
        }
      } else {
#pragma unroll
        for (int r = 0; r < 4; ++r)
          dst[(gr0 + r) * 512 + cr] = f2us(acc[i][j][r] + badd);
      }
    }
  }
}

// ---------------------------------------------------------------------------
// Generic paired GEMM (bf16 out, +bias, opt SiLU). lda = ldb = K.
// ---------------------------------------------------------------------------
struct Gm { const u16* A; const u16* Bt; const u16* bias; u16* C; int mtiles; };

template<int SILU>
__global__ __launch_bounds__(256) void gemm_pair(Gm g0, Gm g1, int ldc, int K)
{
  const Gm G = blockIdx.z ? g1 : g0;
  if ((int)blockIdx.x >= G.mtiles) return;
  const int tid = threadIdx.x;
  const int lane = tid & 63;
  const int wm = (tid >> 6) >> 1, wn = (tid >> 6) & 1;
  const int r16 = lane & 15, rr4 = (lane >> 4) << 2;
  const long row0 = (long)blockIdx.x * 128;
  const long col0 = (long)blockIdx.y * 128;

  f32x4 acc[4][4];
  gemm_core<128,128>(G.A + row0 * (long)K, G.Bt + col0 * (long)K, K, tid, acc);

#pragma unroll
  for (int i = 0; i < 4; ++i) {
    const long gr0 = row0 + wm*64 + i*16 + rr4;
#pragma unroll
    for (int j = 0; j < 4; ++j) {
      const long gc = col0 + wn*64 + j*16 + r16;
      const float badd = us2f(G.bias[gc]);
#pragma unroll
      for (int r = 0; r < 4; ++r) {
        float v = acc[i][j][r] + badd;
        if (SILU) v = v / (1.f + __expf(-v));
        G.C[(gr0 + r) * (long)ldc + gc] = f2us(v);
      }
    }
  }
}

// ---------------------------------------------------------------------------
// Paired fused attention (round-5 structure; NKV/M runtime, z-paired)
// ---------------------------------------------------------------------------
struct AttnSet { const u16* Q; const u16* K; const u16* VT; const float* lb;
                 u16* O; int M; int NKV; };

__global__ __launch_bounds__(256) void attn_pair(AttnSet s0, AttnSet s1)
{
  const AttnSet S = blockIdx.z ? s1 : s0;
  if ((int)blockIdx.x * 128 >= S.M) return;
  constexpr int PLD = 136;
  __shared__ __align__(16) u16 Ps[4][32][PLD];

  const int tid  = threadIdx.x;
  const int lane = tid & 63;
  const int w    = tid >> 6;
  const int bh = blockIdx.y;
  const int b = bh >> 3, h = bh & 7;
  const long q0 = (long)blockIdx.x * 128;
  const int NKV = S.NKV;
  const int NC = NKV >> 7;

  const u16* Qb = S.Q + ((long)b * S.M + q0) * DM + h * DHEAD;
  const u16* Kb = S.K + (long)b * NKV * DM + h * DHEAD;
  const u16* Vb = S.VT + ((long)b * DM + h * DHEAD) * NKV;
  const float* lbb = S.lb + (long)b * NKV;

  const int r16 = lane & 15;
  const int k8  = (lane >> 4) << 3;
  const int rr4 = (lane >> 4) << 2;
  const float SCALE = 0.125f;

  bf16x8 qa[2][2];
#pragma unroll
  for (int i = 0; i < 2; ++i)
#pragma unroll
    for (int kc = 0; kc < 2; ++kc)
      qa[i][kc] = *(const bf16x8*)&Qb[(long)(w*32 + i*16 + r16) * DM + kc*32 + k8];

  f32x4 acc_o[2][4];
#pragma unroll
  for (int i = 0; i < 2; ++i)
#pragma unroll
    for (int jo = 0; jo < 4; ++jo)
      acc_o[i][jo] = (f32x4){0.f, 0.f, 0.f, 0.f};
  float mrow[8], lrow[8];
#pragma unroll
  for (int s = 0; s < 8; ++s) { mrow[s] = -1e30f; lrow[s] = 0.f; }

  for (int c = 0; c < NC; ++c) {
    const int t0 = c * 128;
    f32x4 acc_s[2][8];
#pragma unroll
    for (int i = 0; i < 2; ++i)
#pragma unroll
      for (int j = 0; j < 8; ++j)
        acc_s[i][j] = (f32x4){0.f, 0.f, 0.f, 0.f};
#pragma unroll
    for (int j = 0; j < 8; ++j) {
      const long trow = t0 + j*16 + r16;
      bf16x8 kb0 = *(const bf16x8*)&Kb[trow * DM + k8];
      bf16x8 kb1 = *(const bf16x8*)&Kb[trow * DM + 32 + k8];
#pragma unroll
      for (int i = 0; i < 2; ++i) {
        acc_s[i][j] = __builtin_amdgcn_mfma_f32_16x16x32_bf16(qa[i][0], kb0, acc_s[i][j], 0, 0, 0);
        acc_s[i][j] = __builtin_amdgcn_mfma_f32_16x16x32_bf16(qa[i][1], kb1, acc_s[i][j], 0, 0, 0);
      }
    }

    float lbv[8];
#pragma unroll
    for (int j = 0; j < 8; ++j) lbv[j] = lbb[t0 + j*16 + r16];
    float pm[8];
#pragma unroll
    for (int s = 0; s < 8; ++s) pm[s] = -1e30f;
#pragma unroll
    for (int i = 0; i < 2; ++i)
#pragma unroll
      for (int j = 0; j < 8; ++j)
#pragma unroll
        for (int r = 0; r < 4; ++r) {
          float v = acc_s[i][j][r] * SCALE + lbv[j];
          acc_s[i][j][r] = v;
          pm[i*4 + r] = fmaxf(pm[i*4 + r], v);
        }
#pragma unroll
    for (int s = 0; s < 8; ++s) {
#pragma unroll
      for (int o = 1; o < 16; o <<= 1) pm[s] = fmaxf(pm[s], __shfl_xor(pm[s], o));
    }
    float sc[8];
#pragma unroll
    for (int s = 0; s < 8; ++s) {
      const float mn = fmaxf(mrow[s], pm[s]);
      sc[s] = __expf(mrow[s] - mn);
      mrow[s] = mn;
      lrow[s] *= sc[s];
    }
#pragma unroll
    for (int i = 0; i < 2; ++i)
#pragma unroll
      for (int jo = 0; jo < 4; ++jo)
#pragma unroll
        for (int r = 0; r < 4; ++r)
          acc_o[i][jo][r] *= sc[i*4 + r];

    float ls[8];
#pragma unroll
    for (int s = 0; s < 8; ++s) ls[s] = 0.f;
#pragma unroll
    for (int i = 0; i < 2; ++i)
#pragma unroll
      for (int j = 0; j < 8; ++j)
#pragma unroll
        for (int r = 0; r < 4; ++r) {
          const float p = __expf(acc_s[i][j][r] - mrow[i*4 + r]);
          ls[i*4 + r] += p;
          Ps[w][i*16 + rr4 + r][j*16 + r16] = f2us(p);
        }
#pragma unroll
    for (int s = 0; s < 8; ++s) {
#pragma unroll
      for (int o = 1; o < 16; o <<= 1) ls[s] += __shfl_xor(ls[s], o);
      lrow[s] += ls[s];
    }

    asm volatile("s_waitcnt lgkmcnt(0)" ::: "memory");
    __builtin_amdgcn_sched_barrier(0);

#pragma unroll
    for (int kc = 0; kc < 4; ++kc) {
      bf16x8 pa[2];
#pragma unroll
      for (int i = 0; i < 2; ++i)
        pa[i] = *(const bf16x8*)&Ps[w][i*16 + r16][kc*32 + k8];
#pragma unroll
      for (int jo = 0; jo < 4; ++jo) {
        bf16x8 vb = *(const bf16x8*)&Vb[(long)(jo*16 + r16) * NKV + t0 + kc*32 + k8];
#pragma unroll
        for (int i = 0; i < 2; ++i)
          acc_o[i][jo] = __builtin_amdgcn_mfma_f32_16x16x32_bf16(pa[i], vb, acc_o[i][jo], 0, 0, 0);
      }
    }
    __builtin_amdgcn_sched_barrier(0);
  }

  float linv[8];
#pragma unroll
  for (int s = 0; s < 8; ++s) linv[s] = 1.f / lrow[s];
  u16* Ob = S.O + ((long)b * S.M + q0) * DM + h * DHEAD;
#pragma unroll
  for (int i = 0; i < 2; ++i)
#pragma unroll
    for (int jo = 0; jo < 4; ++jo)
#pragma unroll
      for (int r = 0; r < 4; ++r) {
        const long row = w*32 + i*16 + rr4 + r;
        Ob[row * DM + jo*16 + r16] = f2us(acc_o[i][jo][r] * linv[i*4 + r]);
      }
}

// ---------------------------------------------------------------------------
struct TTab { const u16* in; u16* out; int R, C; };
struct TTable { TTab d[14]; };

__global__ __launch_bounds__(256) void transpose_all(TTable tt)
{
  const TTab d = tt.d[blockIdx.z];
  __shared__ u16 t[32][33];
  const int tx = threadIdx.x & 31, ty = threadIdx.x >> 5;
  for (int r0 = blockIdx.y * 32; r0 < d.R; r0 += gridDim.y * 32) {
    for (int c0 = blockIdx.x * 32; c0 < d.C; c0 += gridDim.x * 32) {
#pragma unroll
      for (int i = 0; i < 4; ++i)
        t[ty + 8*i][tx] = d.in[(long)(r0 + ty + 8*i) * d.C + c0 + tx];
      __syncthreads();
#pragma unroll
      for (int i = 0; i < 4; ++i)
        d.out[(long)(c0 + ty + 8*i) * d.R + r0 + tx] = t[tx][ty + 8*i];
      __syncthreads();
    }
  }
}

// ---------------------------------------------------------------------------
// Paired residual LN: out = LN(X + P), bf16 P, bf16 out (workspace)
// ---------------------------------------------------------------------------
struct LnR { const u16* X; const u16* P; const u16* g; const u16* b; u16* out; int rows; };

__global__ __launch_bounds__(256) void ln_res_pair(LnR a0, LnR a1)
{
  const LnR A = blockIdx.z ? a1 : a0;
  const int row = blockIdx.x * 4 + (threadIdx.x >> 6);
  if (row >= A.rows) return;
  const int lane = threadIdx.x & 63;
  const u16* pr = A.P + (long)row * DM;
  const u16* xr = A.X + (long)row * DM;
  float v[8], s = 0.f, s2 = 0.f;
#pragma unroll
  for (int i = 0; i < 8; ++i) {
    const int jx = i * 64 + lane;
    float t = us2f(pr[jx]) + us2f(xr[jx]);
    v[i] = t; s += t; s2 += t * t;
  }
#pragma unroll
  for (int o = 32; o; o >>= 1) { s += __shfl_xor(s, o); s2 += __shfl_xor(s2, o); }
  const float mean = s * (1.f / DM);
  const float var  = s2 * (1.f / DM) - mean * mean;
  const float rstd = rsqrtf(fmaxf(var, 0.f) + 1e-5f);
#pragma unroll
  for (int i = 0; i < 8; ++i) {
    const int jx = i * 64 + lane;
    A.out[(long)row * DM + jx] = f2us((v[i] - mean) * rstd * us2f(A.g[jx]) + us2f(A.b[jx]));
  }
}

// ---------------------------------------------------------------------------
// Paired final LN: out = LN(P) to d_out (dtype via flag)
// ---------------------------------------------------------------------------
struct LnF { const u16* P; const u16* g; const u16* b; long oofs; int rows; };

__global__ __launch_bounds__(256) void ln_final_pair(LnF a0, LnF a1,
                                                     void* __restrict__ outb,
                                                     const int* __restrict__ flag)
{
  const LnF A = blockIdx.z ? a1 : a0;
  const int row = blockIdx.x * 4 + (threadIdx.x >> 6);
  if (row >= A.rows) return;
  const int lane = threadIdx.x & 63;
  const u16* pr = A.P + (long)row * DM;
  float v[8], s = 0.f, s2 = 0.f;
#pragma unroll
  for (int i = 0; i < 8; ++i) {
    const int jx = i * 64 + lane;
    float t = us2f(pr[jx]);
    v[i] = t; s += t; s2 += t * t;
  }
#pragma unroll
  for (int o = 32; o; o >>= 1) { s += __shfl_xor(s, o); s2 += __shfl_xor(s2, o); }
  const float mean = s * (1.f / DM);
  const float var  = s2 * (1.f / DM) - mean * mean;
  const float rstd = rsqrtf(fmaxf(var, 0.f) + 1e-5f);
  const int isf32 = flag[0];
#pragma unroll
  for (int i = 0; i < 8; ++i) {
    const int jx = i * 64 + lane;
    const float ov = (v[i] - mean) * rstd * us2f(A.g[jx]) + us2f(A.b[jx]);
    if (isf32) ((float*)outb)[A.oofs + (long)row * DM + jx] = ov;
    else       ((u16*)outb)[A.oofs + (long)row * DM + jx] = f2us(ov);
  }
}

// ---------------------------------------------------------------------------
struct Gt { const u16* H; const u16* W2; const u16* b2; long oofs; float* lb; int rows; };

__global__ __launch_bounds__(256) void gate_pair(Gt a0, Gt a1,
                                                 const int* __restrict__ kptr,
                                                 void* __restrict__ outb,
                                                 const int* __restrict__ flag)
{
  const Gt A = blockIdx.z ? a1 : a0;
  const int row = blockIdx.x * 4 + (threadIdx.x >> 6);
  if (row >= A.rows) return;
  const int lane = threadIdx.x & 63;
  const u16* hr = A.H + (long)row * DM;
  float p1 = 0.f, p2 = 0.f, p3 = 0.f;
#pragma unroll
  for (int i = 0; i < 8; ++i) {
    const int idx = i * 64 + lane;
    const float hv = us2f(hr[idx]);
    const u16x4 w = *(const u16x4*)&A.W2[idx * 4];
    p1 += hv * us2f(w[1]);
    p2 += hv * us2f(w[2]); p3 += hv * us2f(w[3]);
  }
#pragma unroll
  for (int o = 32; o; o >>= 1) {
    p1 += __shfl_xor(p1, o);
    p2 += __shfl_xor(p2, o); p3 += __shfl_xor(p3, o);
  }
  if (lane == 0) {
    const float nu = p1 + us2f(A.b2[1]);
    const float al = p2 + us2f(A.b2[2]);
    const float be = p3 + us2f(A.b2[3]);
    auto sp = [](float x) { return x > 20.f ? x : log1pf(expf(x)); };
    const float spn = sp(nu) + 1e-6f;
    const float spa = sp(al);
    const float spb = sp(be) + 1e-6f;
    const float sig = spb / (spn * spa);
    const float kk = (float)kptr[0];
    float gg = expf(-kk * sig);
    gg = fminf(fmaxf(gg, 0.05f), 1.f);
    if (flag[0]) ((float*)outb)[A.oofs + row] = gg;
    else         ((u16*)outb)[A.oofs + row] = f2us(gg);
    A.lb[row] = logf(gg + 1e-12f);
  }
}

// ---------------------------------------------------------------------------
extern "C" void kernel_launch(void* const* d_in, const int* in_sizes, int n_in,
                              void* d_out, int out_size, void* d_ws, size_t ws_size,
                              hipStream_t stream)
{
  const int* kptr = (const int*)d_in[2];

  uint8_t* base = (uint8_t*)d_ws;
  size_t off = 0;
  auto take = [&](size_t bytes) -> void* {
    void* p = base + off;
    off += (bytes + 255) & ~(size_t)255;
    return p;
  };
  int* FLAG = (int*)take(256);

  const int sizes[42] = {
    2097152, 8388608,
    262144, 512, 2048, 4,
    262144, 512, 2048, 4,
    262144,262144,262144,262144, 512,512,512,512, 512,512,
    262144,262144,262144,262144, 512,512,512,512, 512,512,
    1048576, 2048, 1048576, 512, 512, 512,
    1048576, 2048, 1048576, 512, 512, 512
  };
  u16* canon[42];
  u16* cbase = (u16*)take(17319944ul * 2 + 256);
  {
    unsigned long coff = 0;
    for (int i = 0; i < 42; ++i) {
      canon[i] = cbase + coff;
      coff += (unsigned long)((sizes[i] + 7) & ~7);
    }
  }
  const u16 *HdC = canon[0], *HpC = canon[1];
  const u16 *evid_w1 = canon[2], *evid_b1 = canon[3], *evid_w2 = canon[4], *evid_b2 = canon[5];
  const u16 *evip_w1 = canon[6], *evip_b1 = canon[7], *evip_w2 = canon[8], *evip_b2 = canon[9];
  const u16 *p2d_wq = canon[10], *p2d_wk = canon[11], *p2d_wv = canon[12], *p2d_wo = canon[13];
  const u16 *p2d_bq = canon[14], *p2d_bk = canon[15], *p2d_bv = canon[16], *p2d_bo = canon[17];
  const u16 *p2d_lng = canon[18], *p2d_lnb = canon[19];
  const u16 *d2p_wq = canon[20], *d2p_wk = canon[21], *d2p_wv = canon[22], *d2p_wo = canon[23];
  const u16 *d2p_bq = canon[24], *d2p_bk = canon[25], *d2p_bv = canon[26], *d2p_bo = canon[27];
  const u16 *d2p_lng = canon[28], *d2p_lnb = canon[29];
  const u16 *ffnd_w1 = canon[30], *ffnd_b1 = canon[31], *ffnd_w2 = canon[32], *ffnd_b2 = canon[33];
  const u16 *ffnd_lng = canon[34], *ffnd_lnb = canon[35];
  const u16 *ffnp_w1 = canon[36], *ffnp_b1 = canon[37], *ffnp_w2 = canon[38], *ffnp_b2 = canon[39];
  const u16 *ffnp_lng = canon[40], *ffnp_lnb = canon[41];

  // concatenated projection weights (2048 x 512 each)
  u16* HpW = (u16*)take((size_t)2048*512*2);
  u16* HdW = (u16*)take((size_t)2048*512*2);
  u16* woT_p = (u16*)take((size_t)512*512*2);
  u16* woT_d = (u16*)take((size_t)512*512*2);
  u16* ffnp_w1T = (u16*)take((size_t)2048*512*2);
  u16* ffnp_w2T = (u16*)take((size_t)512*2048*2);
  u16* ffnd_w1T = (u16*)take((size_t)2048*512*2);
  u16* ffnd_w2T = (u16*)take((size_t)512*2048*2);

  u16* HBUF_p = (u16*)take((size_t)16384*512*2);   // evi-h p / later PBUF_p
  u16* HBUF_d = (u16*)take((size_t)4096*512*2);    // evi-h d / later PBUF_d
  u16* QBUF_p = (u16*)take((size_t)16384*512*2);
  u16* QBUF_d = (u16*)take((size_t)4096*512*2);
  u16* KBUF_p = (u16*)take((size_t)16384*512*2);
  u16* KBUF_d = (u16*)take((size_t)4096*512*2);
  u16* VT_p   = (u16*)take((size_t)16384*512*2);
  u16* VT_d   = (u16*)take((size_t)4096*512*2);
  u16* ABUF_p = (u16*)take((size_t)16384*512*2);
  u16* ABUF_d = (u16*)take((size_t)4096*512*2);
  u16* HP2  = (u16*)take((size_t)16384*512*2);
  u16* HD2  = (u16*)take((size_t)4096*512*2);
  float* LBD  = (float*)take((size_t)NB*TDr*4);
  float* LBP  = (float*)take((size_t)NB*TPr*4);
  if (off > ws_size) return;

  // aliases (exact-fit reuse; lifetimes verified)
  u16* PBUF_p = HBUF_p;
  u16* PBUF_d = HBUF_d;
  u16* SBUF_p = QBUF_p;                       // 67 MB over QKV+ABUF region
  u16* SBUF_d = SBUF_p + (size_t)16384*2048;  // 16.8 MB

  const long O_HD = 0;
  const long O_HP = 2097152;
  const long O_GD = 10485760;
  const long O_GP = 10489856;

  detect_kernel<<<dim3(1), 64, 0, stream>>>((const u16*)d_in[0], FLAG);
  CvtTable tbl;
  {
    int ii = 0;
    for (int i = 0; i < 43; ++i) {
      if (i == 2) continue;
      tbl.d[ii].src = d_in[i];
      tbl.d[ii].dst_off = (unsigned long)(canon[ii] - cbase);
      tbl.d[ii].n = sizes[ii];
      ++ii;
    }
  }
  cvt_kernel<<<dim3(64, 42), 256, 0, stream>>>(tbl, cbase, FLAG);

  TTable tt;
  {
    const TTab tts[14] = {
      {evip_w1, HpW + 0*512*512, 512, 512},
      {p2d_wq,  HpW + 1*512*512, 512, 512},
      {d2p_wk,  HpW + 2*512*512, 512, 512},
      {d2p_wv,  HpW + 3*512*512, 512, 512},
      {evid_w1, HdW + 0*512*512, 512, 512},
      {d2p_wq,  HdW + 1*512*512, 512, 512},
      {p2d_wk,  HdW + 2*512*512, 512, 512},
      {p2d_wv,  HdW + 3*512*512, 512, 512},
      {p2d_wo, woT_p, 512, 512}, {d2p_wo, woT_d, 512, 512},
      {ffnp_w1, ffnp_w1T, 512, 2048}, {ffnp_w2, ffnp_w2T, 2048, 512},
      {ffnd_w1, ffnd_w1T, 512, 2048}, {ffnd_w2, ffnd_w2T, 2048, 512},
    };
    for (int i = 0; i < 14; ++i) tt.d[i] = tts[i];
  }
  transpose_all<<<dim3(16, 16, 14), 256, 0, stream>>>(tt);

  // ---- fused projections: Hp-set (z=0), Hd-set (z=1) ----
  ProjSet sp{HpC, HpW, evip_b1, p2d_bq, d2p_bk, d2p_bv,
             HBUF_p, QBUF_p, KBUF_p, VT_p, 10, 128};
  ProjSet sd{HdC, HdW, evid_b1, d2p_bq, p2d_bk, p2d_bv,
             HBUF_d, QBUF_d, KBUF_d, VT_d, 8, 32};
  proj_pair<<<dim3(128, 16, 2), 256, 0, stream>>>(sp, sd);

  // ---- gates ----
  Gt gp{HBUF_p, evip_w2, evip_b2, O_GP, LBP, 16384};
  Gt gd{HBUF_d, evid_w2, evid_b2, O_GD, LBD, 4096};
  gate_pair<<<dim3(4096, 1, 2), 256, 0, stream>>>(gp, gd, kptr, d_out, FLAG);

  // ---- attention: z=0 p2d (Q over Hp, KV over Hd), z=1 d2p ----
  AttnSet ap{QBUF_p, KBUF_d, VT_d, LBD, ABUF_p, TPr, TDr};
  AttnSet ad{QBUF_d, KBUF_p, VT_p, LBP, ABUF_d, TDr, TPr};
  attn_pair<<<dim3(8, 128, 2), 256, 0, stream>>>(ap, ad);

  // ---- output projections ----
  Gm wp{ABUF_p, woT_p, p2d_bo, PBUF_p, 128};
  Gm wd{ABUF_d, woT_d, d2p_bo, PBUF_d, 32};
  gemm_pair<0><<<dim3(128, 4, 2), 256, 0, stream>>>(wp, wd, 512, 512);

  // ---- residual LN ----
  LnR lp{HpC, PBUF_p, p2d_lng, p2d_lnb, HP2, 16384};
  LnR ld{HdC, PBUF_d, d2p_lng, d2p_lnb, HD2, 4096};
  ln_res_pair<<<dim3(4096, 1, 2), 256, 0, stream>>>(lp, ld);

  // ---- FFN1 (SiLU) ----
  Gm f1p{HP2, ffnp_w1T, ffnp_b1, SBUF_p, 128};
  Gm f1d{HD2, ffnd_w1T, ffnd_b1, SBUF_d, 32};
  gemm_pair<1><<<dim3(128, 16, 2), 256, 0, stream>>>(f1p, f1d, 2048, 512);

  // ---- FFN2 ----
  Gm f2p{SBUF_p, ffnp_w2T, ffnp_b2, PBUF_p, 128};
  Gm f2d{SBUF_d, ffnd_w2T, ffnd_b2, PBUF_d, 32};
  gemm_pair<0><<<dim3(128, 4, 2), 256, 0, stream>>>(f2p, f2d, 512, 2048);

  // ---- final LN -> d_out ----
  LnF fp{PBUF_p, ffnp_lng, ffnp_lnb, O_HP, 16384};
  LnF fd{PBUF_d, ffnd_lng, ffnd_lnb, O_HD, 4096};
  ln_final_pair<<<dim3(4096, 1, 2), 256, 0, stream>>>(fp, fd, d_out, FLAG);
}

// Round 7
// 435.172 us; speedup vs baseline: 1.5126x; 1.1165x over previous
//
#include <hip/hip_runtime.h>
#include <stdint.h>
#include <math.h>

typedef unsigned short u16;
typedef __attribute__((ext_vector_type(8))) short bf16x8;
typedef __attribute__((ext_vector_type(8))) short short8;
typedef __attribute__((ext_vector_type(4))) float f32x4;
typedef __attribute__((ext_vector_type(4))) unsigned short u16x4;

#define NB 16
#define TDr 256
#define TPr 1024
#define DM 512
#define NH 8
#define DHEAD 64

__device__ __forceinline__ float us2f(u16 u) {
  union { float f; unsigned int i; } x; x.i = ((unsigned int)u) << 16; return x.f;
}
__device__ __forceinline__ u16 f2us(float f) {
  union { float fl; unsigned int i; } x; x.fl = f;
  unsigned int u = x.i;
  return (u16)((u + 0x7fffu + ((u >> 16) & 1u)) >> 16);  // RNE
}

// ---------------------------------------------------------------------------
__global__ __launch_bounds__(64) void detect_kernel(const u16* __restrict__ raw,
                                                    int* __restrict__ flag)
{
  const int lane = threadIdx.x;
  float mx = 0.f;
  for (int i = lane; i < 256; i += 64) {
    float v = us2f(raw[i]);
    v = fabsf(v);
    if (isfinite(v)) mx = fmaxf(mx, v); else mx = 1e30f;
  }
#pragma unroll
  for (int o = 32; o; o >>= 1) mx = fmaxf(mx, __shfl_xor(mx, o));
  if (lane == 0) flag[0] = (mx > 1e10f) ? 1 : 0;
}

// ---------------------------------------------------------------------------
struct CvtDesc { const void* src; unsigned long dst_off; int n; };
struct CvtTable { CvtDesc d[42]; };

__global__ __launch_bounds__(256) void cvt_kernel(CvtTable t, u16* __restrict__ base,
                                                  const int* __restrict__ flag)
{
  const CvtDesc d = t.d[blockIdx.y];
  u16* dst = base + d.dst_off;
  const int isf32 = flag[0];
  const int stride = gridDim.x * 256;
  const int tid0 = blockIdx.x * 256 + threadIdx.x;
  if (d.n >= 8) {
    const int n8 = d.n >> 3;
    if (isf32) {
      const float* s = (const float*)d.src;
      for (int i = tid0; i < n8; i += stride) {
        f32x4 a = *(const f32x4*)&s[i * 8];
        f32x4 b = *(const f32x4*)&s[i * 8 + 4];
        short8 o;
        o[0]=(short)f2us(a[0]); o[1]=(short)f2us(a[1]); o[2]=(short)f2us(a[2]); o[3]=(short)f2us(a[3]);
        o[4]=(short)f2us(b[0]); o[5]=(short)f2us(b[1]); o[6]=(short)f2us(b[2]); o[7]=(short)f2us(b[3]);
        *(short8*)&dst[i * 8] = o;
      }
    } else {
      const short8* s = (const short8*)d.src;
      for (int i = tid0; i < n8; i += stride) *(short8*)&dst[i * 8] = s[i];
    }
  } else {
    if (isf32) {
      const float* s = (const float*)d.src;
      for (int i = tid0; i < d.n; i += stride) dst[i] = f2us(s[i]);
    } else {
      const u16* s = (const u16*)d.src;
      for (int i = tid0; i < d.n; i += stride) dst[i] = s[i];
    }
  }
}

// ---------------------------------------------------------------------------
// Shared GEMM core: 128x128 tile, BK=32, 2-deep global_load_lds pipeline with
// counted vmcnt (verified +13% round 4). lda = ldb = K.
// ---------------------------------------------------------------------------
template<int BM, int BN>
__device__ __forceinline__ void gemm_core(
    const u16* __restrict__ Ab, const u16* __restrict__ Bb,
    int K, int tid, f32x4 (&acc)[BM/32][BN/32])
{
  constexpr int BK = 32;
  constexpr int FM = BM / 32;
  constexpr int FN = BN / 32;
  constexpr int LPT = (BM * BK / 8 + BN * BK / 8) / 256;
  __shared__ __align__(16) u16 As[2][BM * BK];
  __shared__ __align__(16) u16 Bs[2][BN * BK];

  const int lane = tid & 63;
  const int wm = (tid >> 6) >> 1;
  const int wn = (tid >> 6) & 1;

#pragma unroll
  for (int i = 0; i < FM; ++i)
#pragma unroll
    for (int j = 0; j < FN; ++j)
      acc[i][j] = (f32x4){0.f, 0.f, 0.f, 0.f};

  auto stage = [&](int buf, int k0) {
#pragma unroll
    for (int c = tid; c < BM * BK / 8; c += 256) {
      const int r  = c >> 2;
      const int kk = (c & 3) << 3;
      __builtin_amdgcn_global_load_lds(
          (const __attribute__((address_space(1))) uint32_t*)(Ab + (long)r * K + k0 + kk),
          (__attribute__((address_space(3))) uint32_t*)(&As[buf][c * 8]), 16, 0, 0);
    }
#pragma unroll
    for (int c = tid; c < BN * BK / 8; c += 256) {
      const int r  = c >> 2;
      const int kk = (c & 3) << 3;
      __builtin_amdgcn_global_load_lds(
          (const __attribute__((address_space(1))) uint32_t*)(Bb + (long)r * K + k0 + kk),
          (__attribute__((address_space(3))) uint32_t*)(&Bs[buf][c * 8]), 16, 0, 0);
    }
  };

  const int nt = K / BK;
  stage(0, 0);
  if (nt > 1) stage(1, BK);

  for (int t = 0; t < nt; ++t) {
    if (t + 1 < nt) {
      if constexpr (LPT == 4) asm volatile("s_waitcnt vmcnt(4)" ::: "memory");
      else                    asm volatile("s_waitcnt vmcnt(3)" ::: "memory");
    } else {
      asm volatile("s_waitcnt vmcnt(0)" ::: "memory");
    }
    asm volatile("s_barrier" ::: "memory");
    __builtin_amdgcn_sched_barrier(0);

    const int cur = t & 1;
    bf16x8 af[FM], bfv[FN];
#pragma unroll
    for (int i = 0; i < FM; ++i)
      af[i] = *(const bf16x8*)&As[cur][(wm * (BM/2) + i*16 + (lane & 15)) * BK + ((lane >> 4) << 3)];
#pragma unroll
    for (int j = 0; j < FN; ++j)
      bfv[j] = *(const bf16x8*)&Bs[cur][(wn * (BN/2) + j*16 + (lane & 15)) * BK + ((lane >> 4) << 3)];
#pragma unroll
    for (int i = 0; i < FM; ++i)
#pragma unroll
      for (int j = 0; j < FN; ++j)
        acc[i][j] = __builtin_amdgcn_mfma_f32_16x16x32_bf16(af[i], bfv[j], acc[i][j], 0, 0, 0);

    __builtin_amdgcn_sched_barrier(0);
    asm volatile("s_barrier" ::: "memory");
    __builtin_amdgcn_sched_barrier(0);
    if (t + 2 < nt) stage(cur, (t + 2) * BK);
  }
}

// ---------------------------------------------------------------------------
// Fused projection pair: C = A(M,512) @ Wcat(2048,512)^T, epilogue routes
// 512-col ranges: [0:512) evi-h (SiLU), [512:1024) Q, [1024:1536) K,
// [1536:2048) V stored head-transposed VT[b][dcol][t].
// ---------------------------------------------------------------------------
struct ProjSet {
  const u16 *A, *W, *bE, *bQ, *bK, *bV;
  u16 *H, *Q, *Kc, *VT;
  int ntokLog, mtiles;
};

__global__ __launch_bounds__(256) void proj_pair(ProjSet s0, ProjSet s1)
{
  const ProjSet S = blockIdx.z ? s1 : s0;
  if ((int)blockIdx.x >= S.mtiles) return;
  const int tid = threadIdx.x;
  const int lane = tid & 63;
  const int wm = (tid >> 6) >> 1, wn = (tid >> 6) & 1;
  const int r16 = lane & 15, rr4 = (lane >> 4) << 2;
  const long row0 = (long)blockIdx.x * 128;
  const long col0 = (long)blockIdx.y * 128;

  f32x4 acc[4][4];
  gemm_core<128,128>(S.A + row0 * 512, S.W + col0 * 512, 512, tid, acc);

  const int range = (int)(col0 >> 9);
  const u16* bp = range == 0 ? S.bE : range == 1 ? S.bQ : range == 2 ? S.bK : S.bV;
  u16* dst = range == 0 ? S.H : range == 1 ? S.Q : S.Kc;
  const int ntok = 1 << S.ntokLog;

#pragma unroll
  for (int i = 0; i < 4; ++i) {
    const long gr0 = row0 + wm*64 + i*16 + rr4;
#pragma unroll
    for (int j = 0; j < 4; ++j) {
      const int cr = (int)(col0 & 511) + wn*64 + j*16 + r16;
      const float badd = us2f(bp[cr]);
      if (range == 3) {
        const long b = gr0 >> S.ntokLog;
        const long t0 = gr0 & (ntok - 1);
        u16x4 pk;
#pragma unroll
        for (int r = 0; r < 4; ++r) pk[r] = f2us(acc[i][j][r] + badd);
        *(u16x4*)&S.VT[((long)b * 512 + cr) * ntok + t0] = pk;
      } else if (range == 0) {
#pragma unroll
        for (int r = 0; r < 4; ++r) {
          float v = acc[i][j][r] + badd;
          v = v / (1.f + __expf(-v));
          dst[(gr0 + r) * 512 + cr] = f2us(v);
        }
      } else {
#pragma unroll
        for (int r = 0; r < 4; ++r)
          dst[(gr0 + r) * 512 + cr] = f2us(acc[i][j][r] + badd);
      }
    }
  }
}

// ---------------------------------------------------------------------------
// Generic paired GEMM (bf16 out, +bias, opt SiLU). lda = ldb = K.
// ---------------------------------------------------------------------------
struct Gm { const u16* A; const u16* Bt; const u16* bias; u16* C; int mtiles; };

template<int SILU>
__global__ __launch_bounds__(256) void gemm_pair(Gm g0, Gm g1, int ldc, int K)
{
  const Gm G = blockIdx.z ? g1 : g0;
  if ((int)blockIdx.x >= G.mtiles) return;
  const int tid = threadIdx.x;
  const int lane = tid & 63;
  const int wm = (tid >> 6) >> 1, wn = (tid >> 6) & 1;
  const int r16 = lane & 15, rr4 = (lane >> 4) << 2;
  const long row0 = (long)blockIdx.x * 128;
  const long col0 = (long)blockIdx.y * 128;

  f32x4 acc[4][4];
  gemm_core<128,128>(G.A + row0 * (long)K, G.Bt + col0 * (long)K, K, tid, acc);

#pragma unroll
  for (int i = 0; i < 4; ++i) {
    const long gr0 = row0 + wm*64 + i*16 + rr4;
#pragma unroll
    for (int j = 0; j < 4; ++j) {
      const long gc = col0 + wn*64 + j*16 + r16;
      const float badd = us2f(G.bias[gc]);
#pragma unroll
      for (int r = 0; r < 4; ++r) {
        float v = acc[i][j][r] + badd;
        if (SILU) v = v / (1.f + __expf(-v));
        G.C[(gr0 + r) * (long)ldc + gc] = f2us(v);
      }
    }
  }
}

// ---------------------------------------------------------------------------
// Fused attention, compile-time NKV and rows-per-wave (RPW). 4 waves/block,
// QT = 4*RPW q-rows per block; no cross-wave sync. Q/K/V direct from global;
// P bounced through padded LDS (C-layout -> A-layout).
// ---------------------------------------------------------------------------
template<int NKV, int RPW>
__global__ __launch_bounds__(256) void attn_fused(
    const u16* __restrict__ Qp, const u16* __restrict__ Kp,
    const u16* __restrict__ Vt, const float* __restrict__ lb,
    u16* __restrict__ Aout, int M)
{
  constexpr int NC = NKV >> 7;
  constexpr int FI = RPW / 16;
  constexpr int NS = 4 * FI;
  constexpr int QT = 4 * RPW;
  constexpr int PLD = 136;
  __shared__ __align__(16) u16 Ps[4][RPW][PLD];

  const int tid  = threadIdx.x;
  const int lane = tid & 63;
  const int w    = tid >> 6;
  const int bh = blockIdx.y;
  const int b = bh >> 3, h = bh & 7;
  const long q0 = (long)blockIdx.x * QT;

  const u16* Qb = Qp + ((long)b * M + q0) * DM + h * DHEAD;
  const u16* Kb = Kp + (long)b * NKV * DM + h * DHEAD;
  const u16* Vb = Vt + ((long)b * DM + h * DHEAD) * NKV;
  const float* lbb = lb + (long)b * NKV;

  const int r16 = lane & 15;
  const int k8  = (lane >> 4) << 3;
  const int rr4 = (lane >> 4) << 2;
  const float SCALE = 0.125f;

  bf16x8 qa[FI][2];
#pragma unroll
  for (int i = 0; i < FI; ++i)
#pragma unroll
    for (int kc = 0; kc < 2; ++kc)
      qa[i][kc] = *(const bf16x8*)&Qb[(long)(w*RPW + i*16 + r16) * DM + kc*32 + k8];

  f32x4 acc_o[FI][4];
#pragma unroll
  for (int i = 0; i < FI; ++i)
#pragma unroll
    for (int jo = 0; jo < 4; ++jo)
      acc_o[i][jo] = (f32x4){0.f, 0.f, 0.f, 0.f};
  float mrow[NS], lrow[NS];
#pragma unroll
  for (int s = 0; s < NS; ++s) { mrow[s] = -1e30f; lrow[s] = 0.f; }

#pragma unroll
  for (int c = 0; c < NC; ++c) {
    const int t0 = c * 128;
    f32x4 acc_s[FI][8];
#pragma unroll
    for (int i = 0; i < FI; ++i)
#pragma unroll
      for (int j = 0; j < 8; ++j)
        acc_s[i][j] = (f32x4){0.f, 0.f, 0.f, 0.f};
#pragma unroll
    for (int j = 0; j < 8; ++j) {
      const long trow = t0 + j*16 + r16;
      bf16x8 kb0 = *(const bf16x8*)&Kb[trow * DM + k8];
      bf16x8 kb1 = *(const bf16x8*)&Kb[trow * DM + 32 + k8];
#pragma unroll
      for (int i = 0; i < FI; ++i) {
        acc_s[i][j] = __builtin_amdgcn_mfma_f32_16x16x32_bf16(qa[i][0], kb0, acc_s[i][j], 0, 0, 0);
        acc_s[i][j] = __builtin_amdgcn_mfma_f32_16x16x32_bf16(qa[i][1], kb1, acc_s[i][j], 0, 0, 0);
      }
    }

    float lbv[8];
#pragma unroll
    for (int j = 0; j < 8; ++j) lbv[j] = lbb[t0 + j*16 + r16];
    float pm[NS];
#pragma unroll
    for (int s = 0; s < NS; ++s) pm[s] = -1e30f;
#pragma unroll
    for (int i = 0; i < FI; ++i)
#pragma unroll
      for (int j = 0; j < 8; ++j)
#pragma unroll
        for (int r = 0; r < 4; ++r) {
          float v = acc_s[i][j][r] * SCALE + lbv[j];
          acc_s[i][j][r] = v;
          pm[i*4 + r] = fmaxf(pm[i*4 + r], v);
        }
#pragma unroll
    for (int s = 0; s < NS; ++s) {
#pragma unroll
      for (int o = 1; o < 16; o <<= 1) pm[s] = fmaxf(pm[s], __shfl_xor(pm[s], o));
    }
    float sc[NS];
#pragma unroll
    for (int s = 0; s < NS; ++s) {
      const float mn = fmaxf(mrow[s], pm[s]);
      sc[s] = __expf(mrow[s] - mn);
      mrow[s] = mn;
      lrow[s] *= sc[s];
    }
#pragma unroll
    for (int i = 0; i < FI; ++i)
#pragma unroll
      for (int jo = 0; jo < 4; ++jo)
#pragma unroll
        for (int r = 0; r < 4; ++r)
          acc_o[i][jo][r] *= sc[i*4 + r];

    float ls[NS];
#pragma unroll
    for (int s = 0; s < NS; ++s) ls[s] = 0.f;
#pragma unroll
    for (int i = 0; i < FI; ++i)
#pragma unroll
      for (int j = 0; j < 8; ++j)
#pragma unroll
        for (int r = 0; r < 4; ++r) {
          const float p = __expf(acc_s[i][j][r] - mrow[i*4 + r]);
          ls[i*4 + r] += p;
          Ps[w][i*16 + rr4 + r][j*16 + r16] = f2us(p);
        }
#pragma unroll
    for (int s = 0; s < NS; ++s) {
#pragma unroll
      for (int o = 1; o < 16; o <<= 1) ls[s] += __shfl_xor(ls[s], o);
      lrow[s] += ls[s];
    }

    asm volatile("s_waitcnt lgkmcnt(0)" ::: "memory");
    __builtin_amdgcn_sched_barrier(0);

#pragma unroll
    for (int kc = 0; kc < 4; ++kc) {
      bf16x8 pa[FI];
#pragma unroll
      for (int i = 0; i < FI; ++i)
        pa[i] = *(const bf16x8*)&Ps[w][i*16 + r16][kc*32 + k8];
#pragma unroll
      for (int jo = 0; jo < 4; ++jo) {
        bf16x8 vb = *(const bf16x8*)&Vb[(long)(jo*16 + r16) * NKV + t0 + kc*32 + k8];
#pragma unroll
        for (int i = 0; i < FI; ++i)
          acc_o[i][jo] = __builtin_amdgcn_mfma_f32_16x16x32_bf16(pa[i], vb, acc_o[i][jo], 0, 0, 0);
      }
    }
    __builtin_amdgcn_sched_barrier(0);
  }

  float linv[NS];
#pragma unroll
  for (int s = 0; s < NS; ++s) linv[s] = 1.f / lrow[s];
  u16* Ob = Aout + ((long)b * M + q0) * DM + h * DHEAD;
#pragma unroll
  for (int i = 0; i < FI; ++i)
#pragma unroll
    for (int jo = 0; jo < 4; ++jo)
#pragma unroll
      for (int r = 0; r < 4; ++r) {
        const long row = w*RPW + i*16 + rr4 + r;
        Ob[row * DM + jo*16 + r16] = f2us(acc_o[i][jo][r] * linv[i*4 + r]);
      }
}

// ---------------------------------------------------------------------------
struct TTab { const u16* in; u16* out; int R, C; };
struct TTable { TTab d[14]; };

__global__ __launch_bounds__(256) void transpose_all(TTable tt)
{
  const TTab d = tt.d[blockIdx.z];
  __shared__ u16 t[32][33];
  const int tx = threadIdx.x & 31, ty = threadIdx.x >> 5;
  for (int r0 = blockIdx.y * 32; r0 < d.R; r0 += gridDim.y * 32) {
    for (int c0 = blockIdx.x * 32; c0 < d.C; c0 += gridDim.x * 32) {
#pragma unroll
      for (int i = 0; i < 4; ++i)
        t[ty + 8*i][tx] = d.in[(long)(r0 + ty + 8*i) * d.C + c0 + tx];
      __syncthreads();
#pragma unroll
      for (int i = 0; i < 4; ++i)
        d.out[(long)(c0 + ty + 8*i) * d.R + r0 + tx] = t[tx][ty + 8*i];
      __syncthreads();
    }
  }
}

// ---------------------------------------------------------------------------
struct LnR { const u16* X; const u16* P; const u16* g; const u16* b; u16* out; int rows; };

__global__ __launch_bounds__(256) void ln_res_pair(LnR a0, LnR a1)
{
  const LnR A = blockIdx.z ? a1 : a0;
  const int row = blockIdx.x * 4 + (threadIdx.x >> 6);
  if (row >= A.rows) return;
  const int lane = threadIdx.x & 63;
  const u16* pr = A.P + (long)row * DM;
  const u16* xr = A.X + (long)row * DM;
  float v[8], s = 0.f, s2 = 0.f;
#pragma unroll
  for (int i = 0; i < 8; ++i) {
    const int jx = i * 64 + lane;
    float t = us2f(pr[jx]) + us2f(xr[jx]);
    v[i] = t; s += t; s2 += t * t;
  }
#pragma unroll
  for (int o = 32; o; o >>= 1) { s += __shfl_xor(s, o); s2 += __shfl_xor(s2, o); }
  const float mean = s * (1.f / DM);
  const float var  = s2 * (1.f / DM) - mean * mean;
  const float rstd = rsqrtf(fmaxf(var, 0.f) + 1e-5f);
#pragma unroll
  for (int i = 0; i < 8; ++i) {
    const int jx = i * 64 + lane;
    A.out[(long)row * DM + jx] = f2us((v[i] - mean) * rstd * us2f(A.g[jx]) + us2f(A.b[jx]));
  }
}

// ---------------------------------------------------------------------------
struct LnF { const u16* P; const u16* g; const u16* b; long oofs; int rows; };

__global__ __launch_bounds__(256) void ln_final_pair(LnF a0, LnF a1,
                                                     void* __restrict__ outb,
                                                     const int* __restrict__ flag)
{
  const LnF A = blockIdx.z ? a1 : a0;
  const int row = blockIdx.x * 4 + (threadIdx.x >> 6);
  if (row >= A.rows) return;
  const int lane = threadIdx.x & 63;
  const u16* pr = A.P + (long)row * DM;
  float v[8], s = 0.f, s2 = 0.f;
#pragma unroll
  for (int i = 0; i < 8; ++i) {
    const int jx = i * 64 + lane;
    float t = us2f(pr[jx]);
    v[i] = t; s += t; s2 += t * t;
  }
#pragma unroll
  for (int o = 32; o; o >>= 1) { s += __shfl_xor(s, o); s2 += __shfl_xor(s2, o); }
  const float mean = s * (1.f / DM);
  const float var  = s2 * (1.f / DM) - mean * mean;
  const float rstd = rsqrtf(fmaxf(var, 0.f) + 1e-5f);
  const int isf32 = flag[0];
#pragma unroll
  for (int i = 0; i < 8; ++i) {
    const int jx = i * 64 + lane;
    const float ov = (v[i] - mean) * rstd * us2f(A.g[jx]) + us2f(A.b[jx]);
    if (isf32) ((float*)outb)[A.oofs + (long)row * DM + jx] = ov;
    else       ((u16*)outb)[A.oofs + (long)row * DM + jx] = f2us(ov);
  }
}

// ---------------------------------------------------------------------------
struct Gt { const u16* H; const u16* W2; const u16* b2; long oofs; float* lb; int rows; };

__global__ __launch_bounds__(256) void gate_pair(Gt a0, Gt a1,
                                                 const int* __restrict__ kptr,
                                                 void* __restrict__ outb,
                                                 const int* __restrict__ flag)
{
  const Gt A = blockIdx.z ? a1 : a0;
  const int row = blockIdx.x * 4 + (threadIdx.x >> 6);
  if (row >= A.rows) return;
  const int lane = threadIdx.x & 63;
  const u16* hr = A.H + (long)row * DM;
  float p1 = 0.f, p2 = 0.f, p3 = 0.f;
#pragma unroll
  for (int i = 0; i < 8; ++i) {
    const int idx = i * 64 + lane;
    const float hv = us2f(hr[idx]);
    const u16x4 w = *(const u16x4*)&A.W2[idx * 4];
    p1 += hv * us2f(w[1]);
    p2 += hv * us2f(w[2]); p3 += hv * us2f(w[3]);
  }
#pragma unroll
  for (int o = 32; o; o >>= 1) {
    p1 += __shfl_xor(p1, o);
    p2 += __shfl_xor(p2, o); p3 += __shfl_xor(p3, o);
  }
  if (lane == 0) {
    const float nu = p1 + us2f(A.b2[1]);
    const float al = p2 + us2f(A.b2[2]);
    const float be = p3 + us2f(A.b2[3]);
    auto sp = [](float x) { return x > 20.f ? x : log1pf(expf(x)); };
    const float spn = sp(nu) + 1e-6f;
    const float spa = sp(al);
    const float spb = sp(be) + 1e-6f;
    const float sig = spb / (spn * spa);
    const float kk = (float)kptr[0];
    float gg = expf(-kk * sig);
    gg = fminf(fmaxf(gg, 0.05f), 1.f);
    if (flag[0]) ((float*)outb)[A.oofs + row] = gg;
    else         ((u16*)outb)[A.oofs + row] = f2us(gg);
    A.lb[row] = logf(gg + 1e-12f);
  }
}

// ---------------------------------------------------------------------------
extern "C" void kernel_launch(void* const* d_in, const int* in_sizes, int n_in,
                              void* d_out, int out_size, void* d_ws, size_t ws_size,
                              hipStream_t stream)
{
  const int* kptr = (const int*)d_in[2];

  uint8_t* base = (uint8_t*)d_ws;
  size_t off = 0;
  auto take = [&](size_t bytes) -> void* {
    void* p = base + off;
    off += (bytes + 255) & ~(size_t)255;
    return p;
  };
  int* FLAG = (int*)take(256);

  const int sizes[42] = {
    2097152, 8388608,
    262144, 512, 2048, 4,
    262144, 512, 2048, 4,
    262144,262144,262144,262144, 512,512,512,512, 512,512,
    262144,262144,262144,262144, 512,512,512,512, 512,512,
    1048576, 2048, 1048576, 512, 512, 512,
    1048576, 2048, 1048576, 512, 512, 512
  };
  u16* canon[42];
  u16* cbase = (u16*)take(17319944ul * 2 + 256);
  {
    unsigned long coff = 0;
    for (int i = 0; i < 42; ++i) {
      canon[i] = cbase + coff;
      coff += (unsigned long)((sizes[i] + 7) & ~7);
    }
  }
  const u16 *HdC = canon[0], *HpC = canon[1];
  const u16 *evid_w1 = canon[2], *evid_b1 = canon[3], *evid_w2 = canon[4], *evid_b2 = canon[5];
  const u16 *evip_w1 = canon[6], *evip_b1 = canon[7], *evip_w2 = canon[8], *evip_b2 = canon[9];
  const u16 *p2d_wq = canon[10], *p2d_wk = canon[11], *p2d_wv = canon[12], *p2d_wo = canon[13];
  const u16 *p2d_bq = canon[14], *p2d_bk = canon[15], *p2d_bv = canon[16], *p2d_bo = canon[17];
  const u16 *p2d_lng = canon[18], *p2d_lnb = canon[19];
  const u16 *d2p_wq = canon[20], *d2p_wk = canon[21], *d2p_wv = canon[22], *d2p_wo = canon[23];
  const u16 *d2p_bq = canon[24], *d2p_bk = canon[25], *d2p_bv = canon[26], *d2p_bo = canon[27];
  const u16 *d2p_lng = canon[28], *d2p_lnb = canon[29];
  const u16 *ffnd_w1 = canon[30], *ffnd_b1 = canon[31], *ffnd_w2 = canon[32], *ffnd_b2 = canon[33];
  const u16 *ffnd_lng = canon[34], *ffnd_lnb = canon[35];
  const u16 *ffnp_w1 = canon[36], *ffnp_b1 = canon[37], *ffnp_w2 = canon[38], *ffnp_b2 = canon[39];
  const u16 *ffnp_lng = canon[40], *ffnp_lnb = canon[41];

  u16* HpW = (u16*)take((size_t)2048*512*2);
  u16* HdW = (u16*)take((size_t)2048*512*2);
  u16* woT_p = (u16*)take((size_t)512*512*2);
  u16* woT_d = (u16*)take((size_t)512*512*2);
  u16* ffnp_w1T = (u16*)take((size_t)2048*512*2);
  u16* ffnp_w2T = (u16*)take((size_t)512*2048*2);
  u16* ffnd_w1T = (u16*)take((size_t)2048*512*2);
  u16* ffnd_w2T = (u16*)take((size_t)512*2048*2);

  u16* HBUF_p = (u16*)take((size_t)16384*512*2);
  u16* HBUF_d = (u16*)take((size_t)4096*512*2);
  u16* QBUF_p = (u16*)take((size_t)16384*512*2);
  u16* QBUF_d = (u16*)take((size_t)4096*512*2);
  u16* KBUF_p = (u16*)take((size_t)16384*512*2);
  u16* KBUF_d = (u16*)take((size_t)4096*512*2);
  u16* VT_p   = (u16*)take((size_t)16384*512*2);
  u16* VT_d   = (u16*)take((size_t)4096*512*2);
  u16* ABUF_p = (u16*)take((size_t)16384*512*2);
  u16* ABUF_d = (u16*)take((size_t)4096*512*2);
  u16* HP2  = (u16*)take((size_t)16384*512*2);
  u16* HD2  = (u16*)take((size_t)4096*512*2);
  float* LBD  = (float*)take((size_t)NB*TDr*4);
  float* LBP  = (float*)take((size_t)NB*TPr*4);
  if (off > ws_size) return;

  u16* PBUF_p = HBUF_p;
  u16* PBUF_d = HBUF_d;
  u16* SBUF_p = QBUF_p;
  u16* SBUF_d = SBUF_p + (size_t)16384*2048;

  const long O_HD = 0;
  const long O_HP = 2097152;
  const long O_GD = 10485760;
  const long O_GP = 10489856;

  detect_kernel<<<dim3(1), 64, 0, stream>>>((const u16*)d_in[0], FLAG);
  CvtTable tbl;
  {
    int ii = 0;
    for (int i = 0; i < 43; ++i) {
      if (i == 2) continue;
      tbl.d[ii].src = d_in[i];
      tbl.d[ii].dst_off = (unsigned long)(canon[ii] - cbase);
      tbl.d[ii].n = sizes[ii];
      ++ii;
    }
  }
  cvt_kernel<<<dim3(64, 42), 256, 0, stream>>>(tbl, cbase, FLAG);

  TTable tt;
  {
    const TTab tts[14] = {
      {evip_w1, HpW + 0*512*512, 512, 512},
      {p2d_wq,  HpW + 1*512*512, 512, 512},
      {d2p_wk,  HpW + 2*512*512, 512, 512},
      {d2p_wv,  HpW + 3*512*512, 512, 512},
      {evid_w1, HdW + 0*512*512, 512, 512},
      {d2p_wq,  HdW + 1*512*512, 512, 512},
      {p2d_wk,  HdW + 2*512*512, 512, 512},
      {p2d_wv,  HdW + 3*512*512, 512, 512},
      {p2d_wo, woT_p, 512, 512}, {d2p_wo, woT_d, 512, 512},
      {ffnp_w1, ffnp_w1T, 512, 2048}, {ffnp_w2, ffnp_w2T, 2048, 512},
      {ffnd_w1, ffnd_w1T, 512, 2048}, {ffnd_w2, ffnd_w2T, 2048, 512},
    };
    for (int i = 0; i < 14; ++i) tt.d[i] = tts[i];
  }
  transpose_all<<<dim3(16, 16, 14), 256, 0, stream>>>(tt);

  // ---- fused projections ----
  ProjSet sp{HpC, HpW, evip_b1, p2d_bq, d2p_bk, d2p_bv,
             HBUF_p, QBUF_p, KBUF_p, VT_p, 10, 128};
  ProjSet sd{HdC, HdW, evid_b1, d2p_bq, p2d_bk, p2d_bv,
             HBUF_d, QBUF_d, KBUF_d, VT_d, 8, 32};
  proj_pair<<<dim3(128, 16, 2), 256, 0, stream>>>(sp, sd);

  // ---- gates ----
  Gt gp{HBUF_p, evip_w2, evip_b2, O_GP, LBP, 16384};
  Gt gd{HBUF_d, evid_w2, evid_b2, O_GD, LBD, 4096};
  gate_pair<<<dim3(4096, 1, 2), 256, 0, stream>>>(gp, gd, kptr, d_out, FLAG);

  // ---- attention (separate template instantiations; compile-time NC) ----
  attn_fused<TDr,32><<<dim3(TPr/128, NB*NH), 256, 0, stream>>>(
      QBUF_p, KBUF_d, VT_d, LBD, ABUF_p, TPr);
  attn_fused<TPr,16><<<dim3(TDr/64, NB*NH), 256, 0, stream>>>(
      QBUF_d, KBUF_p, VT_p, LBP, ABUF_d, TDr);

  // ---- output projections ----
  Gm wp{ABUF_p, woT_p, p2d_bo, PBUF_p, 128};
  Gm wd{ABUF_d, woT_d, d2p_bo, PBUF_d, 32};
  gemm_pair<0><<<dim3(128, 4, 2), 256, 0, stream>>>(wp, wd, 512, 512);

  // ---- residual LN ----
  LnR lp{HpC, PBUF_p, p2d_lng, p2d_lnb, HP2, 16384};
  LnR ld{HdC, PBUF_d, d2p_lng, d2p_lnb, HD2, 4096};
  ln_res_pair<<<dim3(4096, 1, 2), 256, 0, stream>>>(lp, ld);

  // ---- FFN1 (SiLU) ----
  Gm f1p{HP2, ffnp_w1T, ffnp_b1, SBUF_p, 128};
  Gm f1d{HD2, ffnd_w1T, ffnd_b1, SBUF_d, 32};
  gemm_pair<1><<<dim3(128, 16, 2), 256, 0, stream>>>(f1p, f1d, 2048, 512);

  // ---- FFN2 ----
  Gm f2p{SBUF_p, ffnp_w2T, ffnp_b2, PBUF_p, 128};
  Gm f2d{SBUF_d, ffnd_w2T, ffnd_b2, PBUF_d, 32};
  gemm_pair<0><<<dim3(128, 4, 2), 256, 0, stream>>>(f2p, f2d, 512, 2048);

  // ---- final LN -> d_out ----
  LnF fp{PBUF_p, ffnp_lng, ffnp_lnb, O_HP, 16384};
  LnF fd{PBUF_d, ffnd_lng, ffnd_lnb, O_HD, 4096};
  ln_final_pair<<<dim3(4096, 1, 2), 256, 0, stream>>>(fp, fd, d_out, FLAG);
}